// Round 4
// baseline (1214.671 us; speedup 1.0000x reference)
//
#include <hip/hip_runtime.h>
#include <math.h>
#include <stdint.h>

#define BB 2
#define LL 1024
#define DM 768
#define NL 2
#define VV 50264
#define VPAD 50304   // 393 * 128
#define DS 16
#define DI 1536
#define DR 48
#define DC 4
#define MM (BB*LL)

#define CH 64
#define NC (LL/CH)

#define TS 64
#define KT 16

typedef __attribute__((ext_vector_type(8))) short short8;
typedef __attribute__((ext_vector_type(4))) float f32x4;

#define AS3(p) ((__attribute__((address_space(3))) unsigned int*)(unsigned int)(uintptr_t)(p))
#define AS1(p) ((const __attribute__((address_space(1))) unsigned int*)(uintptr_t)(p))

__device__ __forceinline__ unsigned short f2bf(float v) {
    union { float f; unsigned u; } x; x.f = v;
    unsigned r = x.u + 0x7fffu + ((x.u >> 16) & 1u);
    return (unsigned short)(r >> 16);
}

// ---------------- embedding gather (f32 + bf16) ----------------
__global__ __launch_bounds__(256) void embed_kernel(
    const int* __restrict__ ids, const float* __restrict__ emb,
    float* __restrict__ x, unsigned short* __restrict__ x16)
{
    int m = blockIdx.x;
    int v = ids[m];
    const float* src = emb + (size_t)v * DM;
    float* dst = x + (size_t)m * DM;
    unsigned short* dst16 = x16 + (size_t)m * DM;
    for (int i = threadIdx.x; i < DM; i += 256) {
        float f = src[i];
        dst[i] = f;
        dst16[i] = f2bf(f);
    }
}

// ---------------- emb f32 [VV][DM] -> bf16 [VPAD][DM] (pad rows = 0), vectorized ----------------
__global__ __launch_bounds__(256) void emb_convert_kernel(
    const float* __restrict__ emb, unsigned short* __restrict__ out)
{
    // 8 elements per thread; DM/8 = 96 groups per row
    size_t i8 = (size_t)blockIdx.x * 256 + threadIdx.x;
    size_t row = i8 / 96;
    size_t col8 = (i8 - row * 96) * 8;
    if (row >= VPAD) return;
    ushort4 o0, o1;
    if (row < VV) {
        const float* p = emb + row * DM + col8;
        float4 v0 = *(const float4*)p;
        float4 v1 = *(const float4*)(p + 4);
        o0.x = f2bf(v0.x); o0.y = f2bf(v0.y); o0.z = f2bf(v0.z); o0.w = f2bf(v0.w);
        o1.x = f2bf(v1.x); o1.y = f2bf(v1.y); o1.z = f2bf(v1.z); o1.w = f2bf(v1.w);
    } else {
        o0 = make_ushort4(0, 0, 0, 0);
        o1 = o0;
    }
    unsigned short* op = out + row * DM + col8;
    *(ushort4*)op = o0;
    *(ushort4*)(op + 4) = o1;
}

// ---------------- transpose+convert: in [L][R][C] f32 -> out [L][C][R] bf16 ----------------
__global__ __launch_bounds__(256) void transpose_bf16_kernel(
    const float* __restrict__ in, unsigned short* __restrict__ out, int R, int C)
{
    __shared__ float t[32][33];
    int l = blockIdx.z;
    int r0 = blockIdx.y * 32, c0 = blockIdx.x * 32;
    int tx = threadIdx.x & 31, ty = threadIdx.x >> 5;   // 32 x 8
    const float* ip = in + (size_t)l * R * C;
    unsigned short* op = out + (size_t)l * C * R;
    #pragma unroll
    for (int j = 0; j < 32; j += 8)
        t[ty + j][tx] = ip[(size_t)(r0 + ty + j) * C + c0 + tx];
    __syncthreads();
    #pragma unroll
    for (int j = 0; j < 32; j += 8)
        op[(size_t)(c0 + ty + j) * R + r0 + tx] = f2bf(t[tx][ty + j]);
}

// ---------------- MFMA bf16 GEMM: C = A[M,K] * B[Npad,K]^T (+bias) (+resid) ----------------
// 1-D grid of MT*NTILES blocks; bijective XCD swizzle, m-tile fastest within an
// XCD's contiguous chunk (B-tile stays hot in that XCD's L2 across M-tiles).
template<bool NSTORE>
__global__ __launch_bounds__(256) void gemm_mfma_bt(
    const unsigned short* __restrict__ A, const unsigned short* __restrict__ B,
    const float* __restrict__ bias, const float* __restrict__ resid,
    float* __restrict__ C, int M, int N, int K, int MT, int NTILES)
{
    // XCD-bijective remap (m204)
    int T = MT * NTILES;
    int q = T >> 3, r = T & 7;
    int orig = blockIdx.x;
    int xcd = orig & 7, u = orig >> 3;
    int wg = (xcd < r ? xcd * (q + 1) : r * (q + 1) + (xcd - r) * q) + u;
    int mt = wg % MT, nt = wg / MT;

    __shared__ unsigned short As[128 * 32];
    __shared__ unsigned short Bs[128 * 32];
    int tid = threadIdx.x;
    int w = tid >> 6, lane = tid & 63;
    int m0 = mt * 128, n0 = nt * 128;

    int rA = lane >> 2;
    int kb = (lane & 3) * 8;
    const unsigned short* gA0 = A + (size_t)(m0 + w * 16 + rA) * K + kb;
    const unsigned short* gA1 = gA0 + (size_t)64 * K;
    const unsigned short* gB0 = B + (size_t)(n0 + w * 16 + rA) * K + kb;
    const unsigned short* gB1 = gB0 + (size_t)64 * K;
    unsigned short* lA0 = &As[(w * 16) * 32];
    unsigned short* lA1 = &As[(64 + w * 16) * 32];
    unsigned short* lB0 = &Bs[(w * 16) * 32];
    unsigned short* lB1 = &Bs[(64 + w * 16) * 32];

    int lr = lane & 15, lk = lane >> 4;
    int wr = (w >> 1) * 64, wc = (w & 1) * 64;

    f32x4 acc[4][4] = {};

    for (int k0 = 0; k0 < K; k0 += 32) {
        __builtin_amdgcn_global_load_lds(AS1(gA0 + k0), AS3(lA0), 16, 0, 0);
        __builtin_amdgcn_global_load_lds(AS1(gA1 + k0), AS3(lA1), 16, 0, 0);
        __builtin_amdgcn_global_load_lds(AS1(gB0 + k0), AS3(lB0), 16, 0, 0);
        __builtin_amdgcn_global_load_lds(AS1(gB1 + k0), AS3(lB1), 16, 0, 0);
        __syncthreads();

        short8 a[4], b[4];
        #pragma unroll
        for (int f = 0; f < 4; ++f)
            a[f] = *(const short8*)&As[(wr + f * 16 + lr) * 32 + lk * 8];
        #pragma unroll
        for (int f = 0; f < 4; ++f)
            b[f] = *(const short8*)&Bs[(wc + f * 16 + lr) * 32 + lk * 8];
        #pragma unroll
        for (int i = 0; i < 4; ++i)
            #pragma unroll
            for (int j = 0; j < 4; ++j)
                acc[i][j] = __builtin_amdgcn_mfma_f32_16x16x32_bf16(a[i], b[j], acc[i][j], 0, 0, 0);
        __syncthreads();
    }

    #pragma unroll
    for (int i = 0; i < 4; ++i) {
        int row = m0 + wr + i * 16 + lk * 4;
        #pragma unroll
        for (int j = 0; j < 4; ++j) {
            int col = n0 + wc + j * 16 + lr;
            if (col < N) {
                float bv = bias ? bias[col] : 0.f;
                #pragma unroll
                for (int r2 = 0; r2 < 4; ++r2) {
                    float v = acc[i][j][r2] + bv;
                    if (resid) v += resid[(size_t)(row + r2) * N + col];
                    if (NSTORE)
                        __builtin_nontemporal_store(v, &C[(size_t)(row + r2) * N + col]);
                    else
                        C[(size_t)(row + r2) * N + col] = v;
                }
            }
        }
    }
}

// ---------------- f32 tiled GEMM (small shapes: xproj, dt) ----------------
template<int ACT>
__global__ __launch_bounds__(256) void gemm_tiled(
    const float* __restrict__ A, const float* __restrict__ Bm,
    const float* __restrict__ bias, float* __restrict__ C,
    int M, int N, int K, int lda)
{
    __shared__ float As[KT][TS + 4];
    __shared__ float Bs[KT][TS + 4];
    int tid = threadIdx.x;
    int tx = tid & 15, ty = tid >> 4;
    int m0 = blockIdx.y * TS;
    int n0 = blockIdx.x * TS;
    float acc[4][4] = {};

    for (int k0 = 0; k0 < K; k0 += KT) {
        {
            int i = tid >> 2;
            int k4 = (tid & 3) * 4;
            int m = m0 + i;
            float4 v = make_float4(0.f, 0.f, 0.f, 0.f);
            if (m < M) v = *(const float4*)(A + (size_t)m * lda + k0 + k4);
            As[k4 + 0][i] = v.x; As[k4 + 1][i] = v.y;
            As[k4 + 2][i] = v.z; As[k4 + 3][i] = v.w;
        }
        {
            int k = tid >> 4;
            int j4 = (tid & 15) * 4;
            int n = n0 + j4;
            float4 v = make_float4(0.f, 0.f, 0.f, 0.f);
            const float* p = Bm + (size_t)(k0 + k) * N + n;
            if (n + 3 < N) {
                v = *(const float4*)p;
            } else {
                float t0 = (n + 0 < N) ? p[0] : 0.f;
                float t1 = (n + 1 < N) ? p[1] : 0.f;
                float t2 = (n + 2 < N) ? p[2] : 0.f;
                float t3 = (n + 3 < N) ? p[3] : 0.f;
                v = make_float4(t0, t1, t2, t3);
            }
            Bs[k][j4 + 0] = v.x; Bs[k][j4 + 1] = v.y;
            Bs[k][j4 + 2] = v.z; Bs[k][j4 + 3] = v.w;
        }
        __syncthreads();
        #pragma unroll
        for (int k = 0; k < KT; ++k) {
            float a[4], b[4];
            #pragma unroll
            for (int q = 0; q < 4; ++q) a[q] = As[k][ty * 4 + q];
            #pragma unroll
            for (int q = 0; q < 4; ++q) b[q] = Bs[k][tx * 4 + q];
            #pragma unroll
            for (int i = 0; i < 4; ++i)
                #pragma unroll
                for (int j = 0; j < 4; ++j)
                    acc[i][j] = fmaf(a[i], b[j], acc[i][j]);
        }
        __syncthreads();
    }

    #pragma unroll
    for (int i = 0; i < 4; ++i) {
        int m = m0 + ty * 4 + i;
        if (m >= M) continue;
        #pragma unroll
        for (int j = 0; j < 4; ++j) {
            int n = n0 + tx * 4 + j;
            if (n >= N) continue;
            float v = acc[i][j];
            if (bias)  v += bias[n];
            if (ACT == 1) v = fmaxf(v, 0.f) + log1pf(expf(-fabsf(v)));
            C[(size_t)m * N + n] = v;
        }
    }
}

// ---------------- causal depthwise conv1d + SiLU ----------------
__global__ __launch_bounds__(256) void conv_silu_kernel(
    const float* __restrict__ xr, const float* __restrict__ cw,
    const float* __restrict__ cb, float* __restrict__ u)
{
    int d = blockIdx.x * 256 + threadIdx.x;
    int l = blockIdx.y;
    int b = blockIdx.z;
    float acc = cb[d];
    #pragma unroll
    for (int j = 0; j < DC; ++j) {
        int lp = l - (DC - 1) + j;
        if (lp >= 0)
            acc = fmaf(xr[((size_t)(b * LL + lp)) * (2 * DI) + d], cw[d * DC + j], acc);
    }
    float s = acc / (1.f + expf(-acc));
    u[((size_t)(b * LL + l)) * DI + d] = s;
}

// ---------------- chunked selective scan ----------------
// Phase A: per (b, chunk, d, n): P = prod(dA), Q = chunk-local final state
__global__ __launch_bounds__(256) void scan_reduce_kernel(
    const float* __restrict__ delta, const float* __restrict__ u,
    const float* __restrict__ dbc, const float* __restrict__ A_log,
    float* __restrict__ P, float* __restrict__ Q)
{
    int tid = threadIdx.x;
    int n = tid & 15;
    int d = blockIdx.x * 16 + (tid >> 4);
    int c = blockIdx.y;
    int b = blockIdx.z;

    float Av = -expf(A_log[(size_t)d * DS + n]);
    float inv_Aeps = 1.f / (Av + 1e-7f);

    const float* dp = delta + ((size_t)b * LL + c * CH) * DI + d;
    const float* up = u     + ((size_t)b * LL + c * CH) * DI + d;
    const float* bp = dbc   + ((size_t)b * LL + c * CH) * 80 + DR + n;

    float p = 1.f, s = 0.f;
    for (int l = 0; l < CH; ++l) {
        float dlt = dp[(size_t)l * DI];
        float uv  = up[(size_t)l * DI];
        float Bv  = bp[(size_t)l * 80];
        float dA  = expf(dlt * Av);
        float dBu = (dA - 1.f) * inv_Aeps * Bv * uv;
        p *= dA;
        s = fmaf(dA, s, dBu);
    }
    size_t idx = (((size_t)b * NC + c) * DI + d) * DS + n;
    P[idx] = p;
    Q[idx] = s;
}

// Phase C: chunk-prefix from P,Q inline, then re-run chunk; y emitted as bf16
__global__ __launch_bounds__(256) void scan_apply_kernel(
    const float* __restrict__ delta, const float* __restrict__ u,
    const float* __restrict__ dbc, const float* __restrict__ xr,
    const float* __restrict__ A_log, const float* __restrict__ Dp,
    const float* __restrict__ P, const float* __restrict__ Q,
    unsigned short* __restrict__ y16)
{
    int tid = threadIdx.x;
    int n = tid & 15;
    int d = blockIdx.x * 16 + (tid >> 4);
    int c = blockIdx.y;
    int b = blockIdx.z;

    float Av = -expf(A_log[(size_t)d * DS + n]);
    float Dv = Dp[d];
    float inv_Aeps = 1.f / (Av + 1e-7f);

    // inline prefix over preceding chunks
    float s = 0.f;
    for (int cc = 0; cc < c; ++cc) {
        size_t idx = (((size_t)b * NC + cc) * DI + d) * DS + n;
        s = fmaf(P[idx], s, Q[idx]);
    }

    const float* dp = delta + ((size_t)b * LL + c * CH) * DI + d;
    const float* up = u     + ((size_t)b * LL + c * CH) * DI + d;
    const float* xp = xr    + ((size_t)b * LL + c * CH) * (2 * DI) + DI + d;
    const float* bp = dbc   + ((size_t)b * LL + c * CH) * 80 + DR + n;
    const float* cp = dbc   + ((size_t)b * LL + c * CH) * 80 + DR + DS + n;
    unsigned short* yp = y16 + ((size_t)b * LL + c * CH) * DI + d;

    for (int l = 0; l < CH; ++l) {
        float dlt = dp[(size_t)l * DI];
        float uv  = up[(size_t)l * DI];
        float Bv  = bp[(size_t)l * 80];
        float Cv  = cp[(size_t)l * 80];
        float dA  = expf(dlt * Av);
        float dBu = (dA - 1.f) * inv_Aeps * Bv * uv;
        s = fmaf(dA, s, dBu);
        float pv = s * Cv;
        pv += __shfl_xor(pv, 1);
        pv += __shfl_xor(pv, 2);
        pv += __shfl_xor(pv, 4);
        pv += __shfl_xor(pv, 8);
        if (n == 0) {
            float rv = xp[(size_t)l * (2 * DI)];
            float res = rv / (1.f + expf(-rv));
            yp[(size_t)l * DI] = f2bf((pv + uv * Dv) * res);
        }
    }
}

// ---------------- RMSNorm (optional f32 out, optional bf16 out) ----------------
__global__ __launch_bounds__(256) void rmsnorm_kernel(
    const float* __restrict__ in, const float* __restrict__ w,
    float* __restrict__ outf, unsigned short* __restrict__ outb)
{
    int m = blockIdx.x;
    const float* row = in + (size_t)m * DM;
    float ss = 0.f;
    for (int i = threadIdx.x; i < DM; i += 256) { float v = row[i]; ss = fmaf(v, v, ss); }
    #pragma unroll
    for (int off = 32; off > 0; off >>= 1) ss += __shfl_down(ss, off);
    __shared__ float sred[4];
    __shared__ float sscale;
    int wid = threadIdx.x >> 6;
    if ((threadIdx.x & 63) == 0) sred[wid] = ss;
    __syncthreads();
    if (threadIdx.x == 0) {
        float tot = sred[0] + sred[1] + sred[2] + sred[3];
        sscale = 1.f / sqrtf(tot / (float)DM + 1e-5f);
    }
    __syncthreads();
    float sc = sscale;
    for (int i = threadIdx.x; i < DM; i += 256) {
        float v = row[i] * sc * w[i];
        if (outf) outf[(size_t)m * DM + i] = v;
        if (outb) outb[(size_t)m * DM + i] = f2bf(v);
    }
}

// ---------------- launch ----------------
extern "C" void kernel_launch(void* const* d_in, const int* in_sizes, int n_in,
                              void* d_out, int out_size, void* d_ws, size_t ws_size,
                              hipStream_t stream)
{
    const int*   ids      = (const int*)  d_in[0];
    const float* emb      = (const float*)d_in[1];
    const float* in_w     = (const float*)d_in[2];
    const float* in_b     = (const float*)d_in[3];
    const float* conv_w   = (const float*)d_in[4];
    const float* conv_b   = (const float*)d_in[5];
    const float* xproj_w  = (const float*)d_in[6];
    const float* dt_w     = (const float*)d_in[7];
    const float* dt_b     = (const float*)d_in[8];
    const float* A_log    = (const float*)d_in[9];
    const float* Dp       = (const float*)d_in[10];
    const float* out_w    = (const float*)d_in[11];
    const float* out_b    = (const float*)d_in[12];
    const float* norm_w   = (const float*)d_in[13];
    const float* normf_w  = (const float*)d_in[14];
    float* out = (float*)d_out;

    char* wsp = (char*)d_ws;
    auto alloc = [&](size_t bytes) {
        char* p = wsp;
        wsp += (bytes + 255) & ~(size_t)255;
        return p;
    };
    float* x     = (float*)alloc((size_t)MM * DM * 4);
    float* xr    = (float*)alloc((size_t)MM * 2 * DI * 4);
    float* u     = (float*)alloc((size_t)MM * DI * 4);
    float* dbc   = (float*)alloc((size_t)MM * 80 * 4);
    float* delta = (float*)alloc((size_t)MM * DI * 4);
    float* tmp   = (float*)alloc((size_t)MM * DM * 4);
    float* Pbuf  = (float*)alloc((size_t)BB * NC * DI * DS * 4);
    float* Qbuf  = (float*)alloc((size_t)BB * NC * DI * DS * 4);
    unsigned short* x16     = (unsigned short*)alloc((size_t)MM * DM * 2);
    unsigned short* y16     = (unsigned short*)alloc((size_t)MM * DI * 2);
    unsigned short* emb16   = (unsigned short*)alloc((size_t)VPAD * DM * 2);
    unsigned short* in_wT   = (unsigned short*)alloc((size_t)NL * 2 * DI * DM * 2);
    unsigned short* out_wT  = (unsigned short*)alloc((size_t)NL * DM * DI * 2);

    emb_convert_kernel<<<(VPAD * (DM / 8) + 255) / 256, 256, 0, stream>>>(emb, emb16);
    transpose_bf16_kernel<<<dim3(2 * DI / 32, DM / 32, NL), 256, 0, stream>>>(
        in_w, in_wT, DM, 2 * DI);
    transpose_bf16_kernel<<<dim3(DM / 32, DI / 32, NL), 256, 0, stream>>>(
        out_w, out_wT, DI, DM);

    embed_kernel<<<MM, 256, 0, stream>>>(ids, emb, x, x16);

    for (int layer = 0; layer < NL; ++layer) {
        const float* lb_in  = in_b    + (size_t)layer * 2 * DI;
        const float* lcw    = conv_w  + (size_t)layer * DI * DC;
        const float* lcb    = conv_b  + (size_t)layer * DI;
        const float* lxw    = xproj_w + (size_t)layer * DI * (DR + 2 * DS);
        const float* ldtw   = dt_w    + (size_t)layer * DR * DI;
        const float* ldtb   = dt_b    + (size_t)layer * DI;
        const float* lAlog  = A_log   + (size_t)layer * DI * DS;
        const float* lDp    = Dp      + (size_t)layer * DI;
        const float* lob    = out_b   + (size_t)layer * DM;
        const float* lnw    = norm_w  + (size_t)layer * DM;
        const unsigned short* lw_inT = in_wT  + (size_t)layer * 2 * DI * DM;
        const unsigned short* lw_outT= out_wT + (size_t)layer * DM * DI;

        // xr = x @ in_w + in_b   (M=2048, N=3072, K=768)  [MFMA, swizzled]
        gemm_mfma_bt<false><<<16 * 24, 256, 0, stream>>>(
            x16, lw_inT, lb_in, nullptr, xr, MM, 2 * DI, DM, 16, 24);

        conv_silu_kernel<<<dim3(DI / 256, LL, BB), 256, 0, stream>>>(xr, lcw, lcb, u);

        gemm_tiled<0><<<dim3(2, MM / TS), 256, 0, stream>>>(
            u, lxw, nullptr, dbc, MM, DR + 2 * DS, DI, DI);

        gemm_tiled<1><<<dim3(DI / TS, MM / TS), 256, 0, stream>>>(
            dbc, ldtw, ldtb, delta, MM, DI, DR, DR + 2 * DS);

        scan_reduce_kernel<<<dim3(DI / 16, NC, BB), 256, 0, stream>>>(
            delta, u, dbc, lAlog, Pbuf, Qbuf);
        scan_apply_kernel<<<dim3(DI / 16, NC, BB), 256, 0, stream>>>(
            delta, u, dbc, xr, lAlog, lDp, Pbuf, Qbuf, y16);

        // tmp = y @ out_w + out_b + x   (M x DM, K=DI)  [MFMA, swizzled]
        gemm_mfma_bt<false><<<16 * 6, 256, 0, stream>>>(
            y16, lw_outT, lob, x, tmp, MM, DM, DI, 16, 6);

        // x = rmsnorm(tmp)  (f32 + bf16)
        rmsnorm_kernel<<<MM, 256, 0, stream>>>(tmp, lnw, x, x16);
    }

    // xf = rmsnorm(x)  (bf16 only)
    rmsnorm_kernel<<<MM, 256, 0, stream>>>(x, normf_w, nullptr, x16);

    // logits = xf @ emb^T   (M=2048, N=50264 pad 50304, K=768)  [MFMA, swizzled, NT stores]
    gemm_mfma_bt<true><<<16 * (VPAD / 128), 256, 0, stream>>>(
        x16, emb16, nullptr, nullptr, out, MM, VV, DM, 16, VPAD / 128);
}

// Round 5
// 1184.641 us; speedup vs baseline: 1.0253x; 1.0253x over previous
//
#include <hip/hip_runtime.h>
#include <math.h>
#include <stdint.h>

#define BB 2
#define LL 1024
#define DM 768
#define NL 2
#define VV 50264
#define VPAD 50304   // 393 * 128
#define DS 16
#define DI 1536
#define DR 48
#define DC 4
#define MM (BB*LL)

#define CH 64
#define NC (LL/CH)

#define TS 64
#define KT 16

typedef __attribute__((ext_vector_type(8))) short short8;
typedef __attribute__((ext_vector_type(4))) float f32x4;

#define AS3(p) ((__attribute__((address_space(3))) unsigned int*)(unsigned int)(uintptr_t)(p))
#define AS1(p) ((const __attribute__((address_space(1))) unsigned int*)(uintptr_t)(p))

__device__ __forceinline__ unsigned short f2bf(float v) {
    union { float f; unsigned u; } x; x.f = v;
    unsigned r = x.u + 0x7fffu + ((x.u >> 16) & 1u);
    return (unsigned short)(r >> 16);
}

// ---------------- embedding gather (f32 + bf16) ----------------
__global__ __launch_bounds__(256) void embed_kernel(
    const int* __restrict__ ids, const float* __restrict__ emb,
    float* __restrict__ x, unsigned short* __restrict__ x16)
{
    int m = blockIdx.x;
    int v = ids[m];
    const float* src = emb + (size_t)v * DM;
    float* dst = x + (size_t)m * DM;
    unsigned short* dst16 = x16 + (size_t)m * DM;
    for (int i = threadIdx.x; i < DM; i += 256) {
        float f = src[i];
        dst[i] = f;
        dst16[i] = f2bf(f);
    }
}

// ---------------- emb f32 [VV][DM] -> bf16 [VPAD][DM] (pad rows = 0), vectorized ----------------
__global__ __launch_bounds__(256) void emb_convert_kernel(
    const float* __restrict__ emb, unsigned short* __restrict__ out)
{
    size_t i8 = (size_t)blockIdx.x * 256 + threadIdx.x;
    size_t row = i8 / 96;
    size_t col8 = (i8 - row * 96) * 8;
    if (row >= VPAD) return;
    ushort4 o0, o1;
    if (row < VV) {
        const float* p = emb + row * DM + col8;
        float4 v0 = *(const float4*)p;
        float4 v1 = *(const float4*)(p + 4);
        o0.x = f2bf(v0.x); o0.y = f2bf(v0.y); o0.z = f2bf(v0.z); o0.w = f2bf(v0.w);
        o1.x = f2bf(v1.x); o1.y = f2bf(v1.y); o1.z = f2bf(v1.z); o1.w = f2bf(v1.w);
    } else {
        o0 = make_ushort4(0, 0, 0, 0);
        o1 = o0;
    }
    unsigned short* op = out + row * DM + col8;
    *(ushort4*)op = o0;
    *(ushort4*)(op + 4) = o1;
}

// ---------------- transpose+convert: in [L][R][C] f32 -> out [L][C][R] bf16 ----------------
__global__ __launch_bounds__(256) void transpose_bf16_kernel(
    const float* __restrict__ in, unsigned short* __restrict__ out, int R, int C)
{
    __shared__ float t[32][33];
    int l = blockIdx.z;
    int r0 = blockIdx.y * 32, c0 = blockIdx.x * 32;
    int tx = threadIdx.x & 31, ty = threadIdx.x >> 5;   // 32 x 8
    const float* ip = in + (size_t)l * R * C;
    unsigned short* op = out + (size_t)l * C * R;
    #pragma unroll
    for (int j = 0; j < 32; j += 8)
        t[ty + j][tx] = ip[(size_t)(r0 + ty + j) * C + c0 + tx];
    __syncthreads();
    #pragma unroll
    for (int j = 0; j < 32; j += 8)
        op[(size_t)(c0 + ty + j) * R + r0 + tx] = f2bf(t[tx][ty + j]);
}

// ---------------- MFMA bf16 GEMM: C = A[M,K] * B[Npad,K]^T (+bias) (+resid) ----------------
// 1-D grid of MT*NTILES blocks; bijective XCD swizzle, m-tile fastest within an
// XCD's contiguous chunk (B-tile stays hot in that XCD's L2 across M-tiles).
__global__ __launch_bounds__(256) void gemm_mfma_bt(
    const unsigned short* __restrict__ A, const unsigned short* __restrict__ B,
    const float* __restrict__ bias, const float* __restrict__ resid,
    float* __restrict__ C, int M, int N, int K, int MT, int NTILES)
{
    // XCD-bijective remap (m204)
    int T = MT * NTILES;
    int q = T >> 3, r = T & 7;
    int orig = blockIdx.x;
    int xcd = orig & 7, u = orig >> 3;
    int wg = (xcd < r ? xcd * (q + 1) : r * (q + 1) + (xcd - r) * q) + u;
    int mt = wg % MT, nt = wg / MT;

    __shared__ unsigned short As[128 * 32];
    __shared__ unsigned short Bs[128 * 32];
    int tid = threadIdx.x;
    int w = tid >> 6, lane = tid & 63;
    int m0 = mt * 128, n0 = nt * 128;

    int rA = lane >> 2;
    int kb = (lane & 3) * 8;
    const unsigned short* gA0 = A + (size_t)(m0 + w * 16 + rA) * K + kb;
    const unsigned short* gA1 = gA0 + (size_t)64 * K;
    const unsigned short* gB0 = B + (size_t)(n0 + w * 16 + rA) * K + kb;
    const unsigned short* gB1 = gB0 + (size_t)64 * K;
    unsigned short* lA0 = &As[(w * 16) * 32];
    unsigned short* lA1 = &As[(64 + w * 16) * 32];
    unsigned short* lB0 = &Bs[(w * 16) * 32];
    unsigned short* lB1 = &Bs[(64 + w * 16) * 32];

    int lr = lane & 15, lk = lane >> 4;
    int wr = (w >> 1) * 64, wc = (w & 1) * 64;

    f32x4 acc[4][4] = {};

    for (int k0 = 0; k0 < K; k0 += 32) {
        __builtin_amdgcn_global_load_lds(AS1(gA0 + k0), AS3(lA0), 16, 0, 0);
        __builtin_amdgcn_global_load_lds(AS1(gA1 + k0), AS3(lA1), 16, 0, 0);
        __builtin_amdgcn_global_load_lds(AS1(gB0 + k0), AS3(lB0), 16, 0, 0);
        __builtin_amdgcn_global_load_lds(AS1(gB1 + k0), AS3(lB1), 16, 0, 0);
        __syncthreads();

        short8 a[4], b[4];
        #pragma unroll
        for (int f = 0; f < 4; ++f)
            a[f] = *(const short8*)&As[(wr + f * 16 + lr) * 32 + lk * 8];
        #pragma unroll
        for (int f = 0; f < 4; ++f)
            b[f] = *(const short8*)&Bs[(wc + f * 16 + lr) * 32 + lk * 8];
        #pragma unroll
        for (int i = 0; i < 4; ++i)
            #pragma unroll
            for (int j = 0; j < 4; ++j)
                acc[i][j] = __builtin_amdgcn_mfma_f32_16x16x32_bf16(a[i], b[j], acc[i][j], 0, 0, 0);
        __syncthreads();
    }

    #pragma unroll
    for (int i = 0; i < 4; ++i) {
        int row = m0 + wr + i * 16 + lk * 4;
        #pragma unroll
        for (int j = 0; j < 4; ++j) {
            int col = n0 + wc + j * 16 + lr;
            if (col < N) {
                float bv = bias ? bias[col] : 0.f;
                #pragma unroll
                for (int r2 = 0; r2 < 4; ++r2) {
                    float v = acc[i][j][r2] + bv;
                    if (resid) v += resid[(size_t)(row + r2) * N + col];
                    C[(size_t)(row + r2) * N + col] = v;
                }
            }
        }
    }
}

// ---------------- f32 tiled GEMM (small shapes: xproj, dt) ----------------
template<int ACT>
__global__ __launch_bounds__(256) void gemm_tiled(
    const float* __restrict__ A, const float* __restrict__ Bm,
    const float* __restrict__ bias, float* __restrict__ C,
    int M, int N, int K, int lda)
{
    __shared__ float As[KT][TS + 4];
    __shared__ float Bs[KT][TS + 4];
    int tid = threadIdx.x;
    int tx = tid & 15, ty = tid >> 4;
    int m0 = blockIdx.y * TS;
    int n0 = blockIdx.x * TS;
    float acc[4][4] = {};

    for (int k0 = 0; k0 < K; k0 += KT) {
        {
            int i = tid >> 2;
            int k4 = (tid & 3) * 4;
            int m = m0 + i;
            float4 v = make_float4(0.f, 0.f, 0.f, 0.f);
            if (m < M) v = *(const float4*)(A + (size_t)m * lda + k0 + k4);
            As[k4 + 0][i] = v.x; As[k4 + 1][i] = v.y;
            As[k4 + 2][i] = v.z; As[k4 + 3][i] = v.w;
        }
        {
            int k = tid >> 4;
            int j4 = (tid & 15) * 4;
            int n = n0 + j4;
            float4 v = make_float4(0.f, 0.f, 0.f, 0.f);
            const float* p = Bm + (size_t)(k0 + k) * N + n;
            if (n + 3 < N) {
                v = *(const float4*)p;
            } else {
                float t0 = (n + 0 < N) ? p[0] : 0.f;
                float t1 = (n + 1 < N) ? p[1] : 0.f;
                float t2 = (n + 2 < N) ? p[2] : 0.f;
                float t3 = (n + 3 < N) ? p[3] : 0.f;
                v = make_float4(t0, t1, t2, t3);
            }
            Bs[k][j4 + 0] = v.x; Bs[k][j4 + 1] = v.y;
            Bs[k][j4 + 2] = v.z; Bs[k][j4 + 3] = v.w;
        }
        __syncthreads();
        #pragma unroll
        for (int k = 0; k < KT; ++k) {
            float a[4], b[4];
            #pragma unroll
            for (int q = 0; q < 4; ++q) a[q] = As[k][ty * 4 + q];
            #pragma unroll
            for (int q = 0; q < 4; ++q) b[q] = Bs[k][tx * 4 + q];
            #pragma unroll
            for (int i = 0; i < 4; ++i)
                #pragma unroll
                for (int j = 0; j < 4; ++j)
                    acc[i][j] = fmaf(a[i], b[j], acc[i][j]);
        }
        __syncthreads();
    }

    #pragma unroll
    for (int i = 0; i < 4; ++i) {
        int m = m0 + ty * 4 + i;
        if (m >= M) continue;
        #pragma unroll
        for (int j = 0; j < 4; ++j) {
            int n = n0 + tx * 4 + j;
            if (n >= N) continue;
            float v = acc[i][j];
            if (bias)  v += bias[n];
            if (ACT == 1) v = fmaxf(v, 0.f) + log1pf(expf(-fabsf(v)));
            C[(size_t)m * N + n] = v;
        }
    }
}

// ---------------- causal depthwise conv1d + SiLU ----------------
__global__ __launch_bounds__(256) void conv_silu_kernel(
    const float* __restrict__ xr, const float* __restrict__ cw,
    const float* __restrict__ cb, float* __restrict__ u)
{
    int d = blockIdx.x * 256 + threadIdx.x;
    int l = blockIdx.y;
    int b = blockIdx.z;
    float acc = cb[d];
    #pragma unroll
    for (int j = 0; j < DC; ++j) {
        int lp = l - (DC - 1) + j;
        if (lp >= 0)
            acc = fmaf(xr[((size_t)(b * LL + lp)) * (2 * DI) + d], cw[d * DC + j], acc);
    }
    float s = acc / (1.f + expf(-acc));
    u[((size_t)(b * LL + l)) * DI + d] = s;
}

// ---------------- chunked selective scan ----------------
__global__ __launch_bounds__(256) void scan_reduce_kernel(
    const float* __restrict__ delta, const float* __restrict__ u,
    const float* __restrict__ dbc, const float* __restrict__ A_log,
    float* __restrict__ P, float* __restrict__ Q)
{
    int tid = threadIdx.x;
    int n = tid & 15;
    int d = blockIdx.x * 16 + (tid >> 4);
    int c = blockIdx.y;
    int b = blockIdx.z;

    float Av = -expf(A_log[(size_t)d * DS + n]);
    float inv_Aeps = 1.f / (Av + 1e-7f);

    const float* dp = delta + ((size_t)b * LL + c * CH) * DI + d;
    const float* up = u     + ((size_t)b * LL + c * CH) * DI + d;
    const float* bp = dbc   + ((size_t)b * LL + c * CH) * 80 + DR + n;

    float p = 1.f, s = 0.f;
    for (int l = 0; l < CH; ++l) {
        float dlt = dp[(size_t)l * DI];
        float uv  = up[(size_t)l * DI];
        float Bv  = bp[(size_t)l * 80];
        float dA  = expf(dlt * Av);
        float dBu = (dA - 1.f) * inv_Aeps * Bv * uv;
        p *= dA;
        s = fmaf(dA, s, dBu);
    }
    size_t idx = (((size_t)b * NC + c) * DI + d) * DS + n;
    P[idx] = p;
    Q[idx] = s;
}

__global__ __launch_bounds__(256) void scan_apply_kernel(
    const float* __restrict__ delta, const float* __restrict__ u,
    const float* __restrict__ dbc, const float* __restrict__ xr,
    const float* __restrict__ A_log, const float* __restrict__ Dp,
    const float* __restrict__ P, const float* __restrict__ Q,
    unsigned short* __restrict__ y16)
{
    int tid = threadIdx.x;
    int n = tid & 15;
    int d = blockIdx.x * 16 + (tid >> 4);
    int c = blockIdx.y;
    int b = blockIdx.z;

    float Av = -expf(A_log[(size_t)d * DS + n]);
    float Dv = Dp[d];
    float inv_Aeps = 1.f / (Av + 1e-7f);

    float s = 0.f;
    for (int cc = 0; cc < c; ++cc) {
        size_t idx = (((size_t)b * NC + cc) * DI + d) * DS + n;
        s = fmaf(P[idx], s, Q[idx]);
    }

    const float* dp = delta + ((size_t)b * LL + c * CH) * DI + d;
    const float* up = u     + ((size_t)b * LL + c * CH) * DI + d;
    const float* xp = xr    + ((size_t)b * LL + c * CH) * (2 * DI) + DI + d;
    const float* bp = dbc   + ((size_t)b * LL + c * CH) * 80 + DR + n;
    const float* cp = dbc   + ((size_t)b * LL + c * CH) * 80 + DR + DS + n;
    unsigned short* yp = y16 + ((size_t)b * LL + c * CH) * DI + d;

    for (int l = 0; l < CH; ++l) {
        float dlt = dp[(size_t)l * DI];
        float uv  = up[(size_t)l * DI];
        float Bv  = bp[(size_t)l * 80];
        float Cv  = cp[(size_t)l * 80];
        float dA  = expf(dlt * Av);
        float dBu = (dA - 1.f) * inv_Aeps * Bv * uv;
        s = fmaf(dA, s, dBu);
        float pv = s * Cv;
        pv += __shfl_xor(pv, 1);
        pv += __shfl_xor(pv, 2);
        pv += __shfl_xor(pv, 4);
        pv += __shfl_xor(pv, 8);
        if (n == 0) {
            float rv = xp[(size_t)l * (2 * DI)];
            float res = rv / (1.f + expf(-rv));
            yp[(size_t)l * DI] = f2bf((pv + uv * Dv) * res);
        }
    }
}

// ---------------- RMSNorm (optional f32 out, optional bf16 out) ----------------
__global__ __launch_bounds__(256) void rmsnorm_kernel(
    const float* __restrict__ in, const float* __restrict__ w,
    float* __restrict__ outf, unsigned short* __restrict__ outb)
{
    int m = blockIdx.x;
    const float* row = in + (size_t)m * DM;
    float ss = 0.f;
    for (int i = threadIdx.x; i < DM; i += 256) { float v = row[i]; ss = fmaf(v, v, ss); }
    #pragma unroll
    for (int off = 32; off > 0; off >>= 1) ss += __shfl_down(ss, off);
    __shared__ float sred[4];
    __shared__ float sscale;
    int wid = threadIdx.x >> 6;
    if ((threadIdx.x & 63) == 0) sred[wid] = ss;
    __syncthreads();
    if (threadIdx.x == 0) {
        float tot = sred[0] + sred[1] + sred[2] + sred[3];
        sscale = 1.f / sqrtf(tot / (float)DM + 1e-5f);
    }
    __syncthreads();
    float sc = sscale;
    for (int i = threadIdx.x; i < DM; i += 256) {
        float v = row[i] * sc * w[i];
        if (outf) outf[(size_t)m * DM + i] = v;
        if (outb) outb[(size_t)m * DM + i] = f2bf(v);
    }
}

// ---------------- launch ----------------
extern "C" void kernel_launch(void* const* d_in, const int* in_sizes, int n_in,
                              void* d_out, int out_size, void* d_ws, size_t ws_size,
                              hipStream_t stream)
{
    const int*   ids      = (const int*)  d_in[0];
    const float* emb      = (const float*)d_in[1];
    const float* in_w     = (const float*)d_in[2];
    const float* in_b     = (const float*)d_in[3];
    const float* conv_w   = (const float*)d_in[4];
    const float* conv_b   = (const float*)d_in[5];
    const float* xproj_w  = (const float*)d_in[6];
    const float* dt_w     = (const float*)d_in[7];
    const float* dt_b     = (const float*)d_in[8];
    const float* A_log    = (const float*)d_in[9];
    const float* Dp       = (const float*)d_in[10];
    const float* out_w    = (const float*)d_in[11];
    const float* out_b    = (const float*)d_in[12];
    const float* norm_w   = (const float*)d_in[13];
    const float* normf_w  = (const float*)d_in[14];
    float* out = (float*)d_out;

    char* wsp = (char*)d_ws;
    auto alloc = [&](size_t bytes) {
        char* p = wsp;
        wsp += (bytes + 255) & ~(size_t)255;
        return p;
    };
    float* x     = (float*)alloc((size_t)MM * DM * 4);
    float* xr    = (float*)alloc((size_t)MM * 2 * DI * 4);
    float* u     = (float*)alloc((size_t)MM * DI * 4);
    float* dbc   = (float*)alloc((size_t)MM * 80 * 4);
    float* delta = (float*)alloc((size_t)MM * DI * 4);
    float* tmp   = (float*)alloc((size_t)MM * DM * 4);
    float* Pbuf  = (float*)alloc((size_t)BB * NC * DI * DS * 4);
    float* Qbuf  = (float*)alloc((size_t)BB * NC * DI * DS * 4);
    unsigned short* x16     = (unsigned short*)alloc((size_t)MM * DM * 2);
    unsigned short* y16     = (unsigned short*)alloc((size_t)MM * DI * 2);
    unsigned short* emb16   = (unsigned short*)alloc((size_t)VPAD * DM * 2);
    unsigned short* in_wT   = (unsigned short*)alloc((size_t)NL * 2 * DI * DM * 2);
    unsigned short* out_wT  = (unsigned short*)alloc((size_t)NL * DM * DI * 2);

    emb_convert_kernel<<<(VPAD * (DM / 8) + 255) / 256, 256, 0, stream>>>(emb, emb16);
    transpose_bf16_kernel<<<dim3(2 * DI / 32, DM / 32, NL), 256, 0, stream>>>(
        in_w, in_wT, DM, 2 * DI);
    transpose_bf16_kernel<<<dim3(DM / 32, DI / 32, NL), 256, 0, stream>>>(
        out_w, out_wT, DI, DM);

    embed_kernel<<<MM, 256, 0, stream>>>(ids, emb, x, x16);

    for (int layer = 0; layer < NL; ++layer) {
        const float* lb_in  = in_b    + (size_t)layer * 2 * DI;
        const float* lcw    = conv_w  + (size_t)layer * DI * DC;
        const float* lcb    = conv_b  + (size_t)layer * DI;
        const float* lxw    = xproj_w + (size_t)layer * DI * (DR + 2 * DS);
        const float* ldtw   = dt_w    + (size_t)layer * DR * DI;
        const float* ldtb   = dt_b    + (size_t)layer * DI;
        const float* lAlog  = A_log   + (size_t)layer * DI * DS;
        const float* lDp    = Dp      + (size_t)layer * DI;
        const float* lob    = out_b   + (size_t)layer * DM;
        const float* lnw    = norm_w  + (size_t)layer * DM;
        const unsigned short* lw_inT = in_wT  + (size_t)layer * 2 * DI * DM;
        const unsigned short* lw_outT= out_wT + (size_t)layer * DM * DI;

        // xr = x @ in_w + in_b   (M=2048, N=3072, K=768)  [MFMA, swizzled]
        gemm_mfma_bt<<<16 * 24, 256, 0, stream>>>(
            x16, lw_inT, lb_in, nullptr, xr, MM, 2 * DI, DM, 16, 24);

        conv_silu_kernel<<<dim3(DI / 256, LL, BB), 256, 0, stream>>>(xr, lcw, lcb, u);

        gemm_tiled<0><<<dim3(2, MM / TS), 256, 0, stream>>>(
            u, lxw, nullptr, dbc, MM, DR + 2 * DS, DI, DI);

        gemm_tiled<1><<<dim3(DI / TS, MM / TS), 256, 0, stream>>>(
            dbc, ldtw, ldtb, delta, MM, DI, DR, DR + 2 * DS);

        scan_reduce_kernel<<<dim3(DI / 16, NC, BB), 256, 0, stream>>>(
            delta, u, dbc, lAlog, Pbuf, Qbuf);
        scan_apply_kernel<<<dim3(DI / 16, NC, BB), 256, 0, stream>>>(
            delta, u, dbc, xr, lAlog, lDp, Pbuf, Qbuf, y16);

        // tmp = y @ out_w + out_b + x   (M x DM, K=DI)  [MFMA, swizzled]
        gemm_mfma_bt<<<16 * 6, 256, 0, stream>>>(
            y16, lw_outT, lob, x, tmp, MM, DM, DI, 16, 6);

        // x = rmsnorm(tmp)  (f32 + bf16)
        rmsnorm_kernel<<<MM, 256, 0, stream>>>(tmp, lnw, x, x16);
    }

    // xf = rmsnorm(x)  (bf16 only)
    rmsnorm_kernel<<<MM, 256, 0, stream>>>(x, normf_w, nullptr, x16);

    // logits = xf @ emb^T   (M=2048, N=50264 pad 50304, K=768)  [MFMA, swizzled]
    gemm_mfma_bt<<<16 * (VPAD / 128), 256, 0, stream>>>(
        x16, emb16, nullptr, nullptr, out, MM, VV, DM, 16, VPAD / 128);
}

// Round 6
// 1143.507 us; speedup vs baseline: 1.0622x; 1.0360x over previous
//
#include <hip/hip_runtime.h>
#include <math.h>
#include <stdint.h>

#define BB 2
#define LL 1024
#define DM 768
#define NL 2
#define VV 50264
#define VPAD 50304   // 393 * 128
#define DS 16
#define DI 1536
#define DR 48
#define DC 4
#define MM (BB*LL)

#define CH 64
#define NC (LL/CH)

#define TS 64
#define KT 16

typedef __attribute__((ext_vector_type(8))) short short8;
typedef __attribute__((ext_vector_type(4))) float f32x4;

#define AS3(p) ((__attribute__((address_space(3))) unsigned int*)(unsigned int)(uintptr_t)(p))
#define AS1(p) ((const __attribute__((address_space(1))) unsigned int*)(uintptr_t)(p))

__device__ __forceinline__ unsigned short f2bf(float v) {
    union { float f; unsigned u; } x; x.f = v;
    unsigned r = x.u + 0x7fffu + ((x.u >> 16) & 1u);
    return (unsigned short)(r >> 16);
}

// ---------------- embedding gather (f32 + bf16) ----------------
__global__ __launch_bounds__(256) void embed_kernel(
    const int* __restrict__ ids, const float* __restrict__ emb,
    float* __restrict__ x, unsigned short* __restrict__ x16)
{
    int m = blockIdx.x;
    int v = ids[m];
    const float* src = emb + (size_t)v * DM;
    float* dst = x + (size_t)m * DM;
    unsigned short* dst16 = x16 + (size_t)m * DM;
    for (int i = threadIdx.x; i < DM; i += 256) {
        float f = src[i];
        dst[i] = f;
        dst16[i] = f2bf(f);
    }
}

// ---------------- emb f32 [VV][DM] -> bf16 [VPAD][DM] (pad rows = 0), vectorized ----------------
__global__ __launch_bounds__(256) void emb_convert_kernel(
    const float* __restrict__ emb, unsigned short* __restrict__ out)
{
    size_t i8 = (size_t)blockIdx.x * 256 + threadIdx.x;
    size_t row = i8 / 96;
    size_t col8 = (i8 - row * 96) * 8;
    if (row >= VPAD) return;
    ushort4 o0, o1;
    if (row < VV) {
        const float* p = emb + row * DM + col8;
        float4 v0 = *(const float4*)p;
        float4 v1 = *(const float4*)(p + 4);
        o0.x = f2bf(v0.x); o0.y = f2bf(v0.y); o0.z = f2bf(v0.z); o0.w = f2bf(v0.w);
        o1.x = f2bf(v1.x); o1.y = f2bf(v1.y); o1.z = f2bf(v1.z); o1.w = f2bf(v1.w);
    } else {
        o0 = make_ushort4(0, 0, 0, 0);
        o1 = o0;
    }
    unsigned short* op = out + row * DM + col8;
    *(ushort4*)op = o0;
    *(ushort4*)(op + 4) = o1;
}

// ---------------- transpose+convert: in [L][R][C] f32 -> out [L][C][R] bf16 ----------------
__global__ __launch_bounds__(256) void transpose_bf16_kernel(
    const float* __restrict__ in, unsigned short* __restrict__ out, int R, int C)
{
    __shared__ float t[32][33];
    int l = blockIdx.z;
    int r0 = blockIdx.y * 32, c0 = blockIdx.x * 32;
    int tx = threadIdx.x & 31, ty = threadIdx.x >> 5;   // 32 x 8
    const float* ip = in + (size_t)l * R * C;
    unsigned short* op = out + (size_t)l * C * R;
    #pragma unroll
    for (int j = 0; j < 32; j += 8)
        t[ty + j][tx] = ip[(size_t)(r0 + ty + j) * C + c0 + tx];
    __syncthreads();
    #pragma unroll
    for (int j = 0; j < 32; j += 8)
        op[(size_t)(c0 + ty + j) * R + r0 + tx] = f2bf(t[tx][ty + j]);
}

// ---------------- MFMA bf16 GEMM: C = A[M,K] * B[Npad,K]^T (+bias) (+resid) ----------------
// 128x128 tile, BK=32, 4 waves. 2-phase double-buffered staging: next K-tile's
// global_load_lds issued before current tile's MFMA; one barrier per K-step
// (its implicit vmcnt(0) is the pipeline wait). XCD-bijective swizzle,
// m-tile fastest within an XCD chunk.
__global__ __launch_bounds__(256) void gemm_mfma_bt(
    const unsigned short* __restrict__ A, const unsigned short* __restrict__ B,
    const float* __restrict__ bias, const float* __restrict__ resid,
    float* __restrict__ C, int M, int N, int K, int MT, int NTILES)
{
    // XCD-bijective remap (m204)
    int T = MT * NTILES;
    int q = T >> 3, r = T & 7;
    int orig = blockIdx.x;
    int xcd = orig & 7, u = orig >> 3;
    int wg = (xcd < r ? xcd * (q + 1) : r * (q + 1) + (xcd - r) * q) + u;
    int mt = wg % MT, nt = wg / MT;

    __shared__ unsigned short As[2][128 * 32];
    __shared__ unsigned short Bs[2][128 * 32];
    int tid = threadIdx.x;
    int w = tid >> 6, lane = tid & 63;
    int m0 = mt * 128, n0 = nt * 128;

    int rA = lane >> 2;            // row within 16-row group
    int kb = (lane & 3) * 8;       // bf16 offset within row
    const unsigned short* gA0 = A + (size_t)(m0 + w * 16 + rA) * K + kb;
    const unsigned short* gA1 = gA0 + (size_t)64 * K;
    const unsigned short* gB0 = B + (size_t)(n0 + w * 16 + rA) * K + kb;
    const unsigned short* gB1 = gB0 + (size_t)64 * K;

    int lr = lane & 15, lk = lane >> 4;
    int wr = (w >> 1) * 64, wc = (w & 1) * 64;

    f32x4 acc[4][4] = {};

#define STAGE(k0, buf) do { \
    __builtin_amdgcn_global_load_lds(AS1(gA0 + (k0)), AS3(&As[buf][(w * 16) * 32]), 16, 0, 0); \
    __builtin_amdgcn_global_load_lds(AS1(gA1 + (k0)), AS3(&As[buf][(64 + w * 16) * 32]), 16, 0, 0); \
    __builtin_amdgcn_global_load_lds(AS1(gB0 + (k0)), AS3(&Bs[buf][(w * 16) * 32]), 16, 0, 0); \
    __builtin_amdgcn_global_load_lds(AS1(gB1 + (k0)), AS3(&Bs[buf][(64 + w * 16) * 32]), 16, 0, 0); \
} while (0)

#define COMPUTE(buf) do { \
    short8 a[4], b[4]; \
    _Pragma("unroll") \
    for (int f = 0; f < 4; ++f) \
        a[f] = *(const short8*)&As[buf][(wr + f * 16 + lr) * 32 + lk * 8]; \
    _Pragma("unroll") \
    for (int f = 0; f < 4; ++f) \
        b[f] = *(const short8*)&Bs[buf][(wc + f * 16 + lr) * 32 + lk * 8]; \
    _Pragma("unroll") \
    for (int i = 0; i < 4; ++i) \
        _Pragma("unroll") \
        for (int j = 0; j < 4; ++j) \
            acc[i][j] = __builtin_amdgcn_mfma_f32_16x16x32_bf16(a[i], b[j], acc[i][j], 0, 0, 0); \
} while (0)

    int nsteps = K / 32;
    STAGE(0, 0);
    __syncthreads();                 // drains vmcnt(0): buf0 ready
    int cur = 0;
    for (int t = 0; t < nsteps - 1; ++t) {
        STAGE((t + 1) * 32, cur ^ 1);  // issue next tile first (prefetch)
        COMPUTE(cur);                  // MFMA on current tile overlaps loads
        __syncthreads();               // drains vmcnt(0): buf^1 ready; all reads of cur done
        cur ^= 1;
    }
    COMPUTE(cur);

#undef STAGE
#undef COMPUTE

    #pragma unroll
    for (int i = 0; i < 4; ++i) {
        int row = m0 + wr + i * 16 + lk * 4;
        #pragma unroll
        for (int j = 0; j < 4; ++j) {
            int col = n0 + wc + j * 16 + lr;
            if (col < N) {
                float bv = bias ? bias[col] : 0.f;
                #pragma unroll
                for (int r2 = 0; r2 < 4; ++r2) {
                    float v = acc[i][j][r2] + bv;
                    if (resid) v += resid[(size_t)(row + r2) * N + col];
                    C[(size_t)(row + r2) * N + col] = v;
                }
            }
        }
    }
}

// ---------------- f32 tiled GEMM (small shapes: xproj, dt) ----------------
template<int ACT>
__global__ __launch_bounds__(256) void gemm_tiled(
    const float* __restrict__ A, const float* __restrict__ Bm,
    const float* __restrict__ bias, float* __restrict__ C,
    int M, int N, int K, int lda)
{
    __shared__ float As[KT][TS + 4];
    __shared__ float Bs[KT][TS + 4];
    int tid = threadIdx.x;
    int tx = tid & 15, ty = tid >> 4;
    int m0 = blockIdx.y * TS;
    int n0 = blockIdx.x * TS;
    float acc[4][4] = {};

    for (int k0 = 0; k0 < K; k0 += KT) {
        {
            int i = tid >> 2;
            int k4 = (tid & 3) * 4;
            int m = m0 + i;
            float4 v = make_float4(0.f, 0.f, 0.f, 0.f);
            if (m < M) v = *(const float4*)(A + (size_t)m * lda + k0 + k4);
            As[k4 + 0][i] = v.x; As[k4 + 1][i] = v.y;
            As[k4 + 2][i] = v.z; As[k4 + 3][i] = v.w;
        }
        {
            int k = tid >> 4;
            int j4 = (tid & 15) * 4;
            int n = n0 + j4;
            float4 v = make_float4(0.f, 0.f, 0.f, 0.f);
            const float* p = Bm + (size_t)(k0 + k) * N + n;
            if (n + 3 < N) {
                v = *(const float4*)p;
            } else {
                float t0 = (n + 0 < N) ? p[0] : 0.f;
                float t1 = (n + 1 < N) ? p[1] : 0.f;
                float t2 = (n + 2 < N) ? p[2] : 0.f;
                float t3 = (n + 3 < N) ? p[3] : 0.f;
                v = make_float4(t0, t1, t2, t3);
            }
            Bs[k][j4 + 0] = v.x; Bs[k][j4 + 1] = v.y;
            Bs[k][j4 + 2] = v.z; Bs[k][j4 + 3] = v.w;
        }
        __syncthreads();
        #pragma unroll
        for (int k = 0; k < KT; ++k) {
            float a[4], b[4];
            #pragma unroll
            for (int q = 0; q < 4; ++q) a[q] = As[k][ty * 4 + q];
            #pragma unroll
            for (int q = 0; q < 4; ++q) b[q] = Bs[k][tx * 4 + q];
            #pragma unroll
            for (int i = 0; i < 4; ++i)
                #pragma unroll
                for (int j = 0; j < 4; ++j)
                    acc[i][j] = fmaf(a[i], b[j], acc[i][j]);
        }
        __syncthreads();
    }

    #pragma unroll
    for (int i = 0; i < 4; ++i) {
        int m = m0 + ty * 4 + i;
        if (m >= M) continue;
        #pragma unroll
        for (int j = 0; j < 4; ++j) {
            int n = n0 + tx * 4 + j;
            if (n >= N) continue;
            float v = acc[i][j];
            if (bias)  v += bias[n];
            if (ACT == 1) v = fmaxf(v, 0.f) + log1pf(expf(-fabsf(v)));
            C[(size_t)m * N + n] = v;
        }
    }
}

// ---------------- causal depthwise conv1d + SiLU ----------------
__global__ __launch_bounds__(256) void conv_silu_kernel(
    const float* __restrict__ xr, const float* __restrict__ cw,
    const float* __restrict__ cb, float* __restrict__ u)
{
    int d = blockIdx.x * 256 + threadIdx.x;
    int l = blockIdx.y;
    int b = blockIdx.z;
    float acc = cb[d];
    #pragma unroll
    for (int j = 0; j < DC; ++j) {
        int lp = l - (DC - 1) + j;
        if (lp >= 0)
            acc = fmaf(xr[((size_t)(b * LL + lp)) * (2 * DI) + d], cw[d * DC + j], acc);
    }
    float s = acc / (1.f + expf(-acc));
    u[((size_t)(b * LL + l)) * DI + d] = s;
}

// ---------------- chunked selective scan ----------------
__global__ __launch_bounds__(256) void scan_reduce_kernel(
    const float* __restrict__ delta, const float* __restrict__ u,
    const float* __restrict__ dbc, const float* __restrict__ A_log,
    float* __restrict__ P, float* __restrict__ Q)
{
    int tid = threadIdx.x;
    int n = tid & 15;
    int d = blockIdx.x * 16 + (tid >> 4);
    int c = blockIdx.y;
    int b = blockIdx.z;

    float Av = -expf(A_log[(size_t)d * DS + n]);
    float inv_Aeps = 1.f / (Av + 1e-7f);

    const float* dp = delta + ((size_t)b * LL + c * CH) * DI + d;
    const float* up = u     + ((size_t)b * LL + c * CH) * DI + d;
    const float* bp = dbc   + ((size_t)b * LL + c * CH) * 80 + DR + n;

    float p = 1.f, s = 0.f;
    for (int l = 0; l < CH; ++l) {
        float dlt = dp[(size_t)l * DI];
        float uv  = up[(size_t)l * DI];
        float Bv  = bp[(size_t)l * 80];
        float dA  = expf(dlt * Av);
        float dBu = (dA - 1.f) * inv_Aeps * Bv * uv;
        p *= dA;
        s = fmaf(dA, s, dBu);
    }
    size_t idx = (((size_t)b * NC + c) * DI + d) * DS + n;
    P[idx] = p;
    Q[idx] = s;
}

__global__ __launch_bounds__(256) void scan_apply_kernel(
    const float* __restrict__ delta, const float* __restrict__ u,
    const float* __restrict__ dbc, const float* __restrict__ xr,
    const float* __restrict__ A_log, const float* __restrict__ Dp,
    const float* __restrict__ P, const float* __restrict__ Q,
    unsigned short* __restrict__ y16)
{
    int tid = threadIdx.x;
    int n = tid & 15;
    int d = blockIdx.x * 16 + (tid >> 4);
    int c = blockIdx.y;
    int b = blockIdx.z;

    float Av = -expf(A_log[(size_t)d * DS + n]);
    float Dv = Dp[d];
    float inv_Aeps = 1.f / (Av + 1e-7f);

    float s = 0.f;
    for (int cc = 0; cc < c; ++cc) {
        size_t idx = (((size_t)b * NC + cc) * DI + d) * DS + n;
        s = fmaf(P[idx], s, Q[idx]);
    }

    const float* dp = delta + ((size_t)b * LL + c * CH) * DI + d;
    const float* up = u     + ((size_t)b * LL + c * CH) * DI + d;
    const float* xp = xr    + ((size_t)b * LL + c * CH) * (2 * DI) + DI + d;
    const float* bp = dbc   + ((size_t)b * LL + c * CH) * 80 + DR + n;
    const float* cp = dbc   + ((size_t)b * LL + c * CH) * 80 + DR + DS + n;
    unsigned short* yp = y16 + ((size_t)b * LL + c * CH) * DI + d;

    for (int l = 0; l < CH; ++l) {
        float dlt = dp[(size_t)l * DI];
        float uv  = up[(size_t)l * DI];
        float Bv  = bp[(size_t)l * 80];
        float Cv  = cp[(size_t)l * 80];
        float dA  = expf(dlt * Av);
        float dBu = (dA - 1.f) * inv_Aeps * Bv * uv;
        s = fmaf(dA, s, dBu);
        float pv = s * Cv;
        pv += __shfl_xor(pv, 1);
        pv += __shfl_xor(pv, 2);
        pv += __shfl_xor(pv, 4);
        pv += __shfl_xor(pv, 8);
        if (n == 0) {
            float rv = xp[(size_t)l * (2 * DI)];
            float res = rv / (1.f + expf(-rv));
            yp[(size_t)l * DI] = f2bf((pv + uv * Dv) * res);
        }
    }
}

// ---------------- RMSNorm (optional f32 out, optional bf16 out) ----------------
__global__ __launch_bounds__(256) void rmsnorm_kernel(
    const float* __restrict__ in, const float* __restrict__ w,
    float* __restrict__ outf, unsigned short* __restrict__ outb)
{
    int m = blockIdx.x;
    const float* row = in + (size_t)m * DM;
    float ss = 0.f;
    for (int i = threadIdx.x; i < DM; i += 256) { float v = row[i]; ss = fmaf(v, v, ss); }
    #pragma unroll
    for (int off = 32; off > 0; off >>= 1) ss += __shfl_down(ss, off);
    __shared__ float sred[4];
    __shared__ float sscale;
    int wid = threadIdx.x >> 6;
    if ((threadIdx.x & 63) == 0) sred[wid] = ss;
    __syncthreads();
    if (threadIdx.x == 0) {
        float tot = sred[0] + sred[1] + sred[2] + sred[3];
        sscale = 1.f / sqrtf(tot / (float)DM + 1e-5f);
    }
    __syncthreads();
    float sc = sscale;
    for (int i = threadIdx.x; i < DM; i += 256) {
        float v = row[i] * sc * w[i];
        if (outf) outf[(size_t)m * DM + i] = v;
        if (outb) outb[(size_t)m * DM + i] = f2bf(v);
    }
}

// ---------------- launch ----------------
extern "C" void kernel_launch(void* const* d_in, const int* in_sizes, int n_in,
                              void* d_out, int out_size, void* d_ws, size_t ws_size,
                              hipStream_t stream)
{
    const int*   ids      = (const int*)  d_in[0];
    const float* emb      = (const float*)d_in[1];
    const float* in_w     = (const float*)d_in[2];
    const float* in_b     = (const float*)d_in[3];
    const float* conv_w   = (const float*)d_in[4];
    const float* conv_b   = (const float*)d_in[5];
    const float* xproj_w  = (const float*)d_in[6];
    const float* dt_w     = (const float*)d_in[7];
    const float* dt_b     = (const float*)d_in[8];
    const float* A_log    = (const float*)d_in[9];
    const float* Dp       = (const float*)d_in[10];
    const float* out_w    = (const float*)d_in[11];
    const float* out_b    = (const float*)d_in[12];
    const float* norm_w   = (const float*)d_in[13];
    const float* normf_w  = (const float*)d_in[14];
    float* out = (float*)d_out;

    char* wsp = (char*)d_ws;
    auto alloc = [&](size_t bytes) {
        char* p = wsp;
        wsp += (bytes + 255) & ~(size_t)255;
        return p;
    };
    float* x     = (float*)alloc((size_t)MM * DM * 4);
    float* xr    = (float*)alloc((size_t)MM * 2 * DI * 4);
    float* u     = (float*)alloc((size_t)MM * DI * 4);
    float* dbc   = (float*)alloc((size_t)MM * 80 * 4);
    float* delta = (float*)alloc((size_t)MM * DI * 4);
    float* tmp   = (float*)alloc((size_t)MM * DM * 4);
    float* Pbuf  = (float*)alloc((size_t)BB * NC * DI * DS * 4);
    float* Qbuf  = (float*)alloc((size_t)BB * NC * DI * DS * 4);
    unsigned short* x16     = (unsigned short*)alloc((size_t)MM * DM * 2);
    unsigned short* y16     = (unsigned short*)alloc((size_t)MM * DI * 2);
    unsigned short* emb16   = (unsigned short*)alloc((size_t)VPAD * DM * 2);
    unsigned short* in_wT   = (unsigned short*)alloc((size_t)NL * 2 * DI * DM * 2);
    unsigned short* out_wT  = (unsigned short*)alloc((size_t)NL * DM * DI * 2);

    emb_convert_kernel<<<(VPAD * (DM / 8) + 255) / 256, 256, 0, stream>>>(emb, emb16);
    transpose_bf16_kernel<<<dim3(2 * DI / 32, DM / 32, NL), 256, 0, stream>>>(
        in_w, in_wT, DM, 2 * DI);
    transpose_bf16_kernel<<<dim3(DM / 32, DI / 32, NL), 256, 0, stream>>>(
        out_w, out_wT, DI, DM);

    embed_kernel<<<MM, 256, 0, stream>>>(ids, emb, x, x16);

    for (int layer = 0; layer < NL; ++layer) {
        const float* lb_in  = in_b    + (size_t)layer * 2 * DI;
        const float* lcw    = conv_w  + (size_t)layer * DI * DC;
        const float* lcb    = conv_b  + (size_t)layer * DI;
        const float* lxw    = xproj_w + (size_t)layer * DI * (DR + 2 * DS);
        const float* ldtw   = dt_w    + (size_t)layer * DR * DI;
        const float* ldtb   = dt_b    + (size_t)layer * DI;
        const float* lAlog  = A_log   + (size_t)layer * DI * DS;
        const float* lDp    = Dp      + (size_t)layer * DI;
        const float* lob    = out_b   + (size_t)layer * DM;
        const float* lnw    = norm_w  + (size_t)layer * DM;
        const unsigned short* lw_inT = in_wT  + (size_t)layer * 2 * DI * DM;
        const unsigned short* lw_outT= out_wT + (size_t)layer * DM * DI;

        // xr = x @ in_w + in_b   (M=2048, N=3072, K=768)  [MFMA, 2-phase]
        gemm_mfma_bt<<<16 * 24, 256, 0, stream>>>(
            x16, lw_inT, lb_in, nullptr, xr, MM, 2 * DI, DM, 16, 24);

        conv_silu_kernel<<<dim3(DI / 256, LL, BB), 256, 0, stream>>>(xr, lcw, lcb, u);

        gemm_tiled<0><<<dim3(2, MM / TS), 256, 0, stream>>>(
            u, lxw, nullptr, dbc, MM, DR + 2 * DS, DI, DI);

        gemm_tiled<1><<<dim3(DI / TS, MM / TS), 256, 0, stream>>>(
            dbc, ldtw, ldtb, delta, MM, DI, DR, DR + 2 * DS);

        scan_reduce_kernel<<<dim3(DI / 16, NC, BB), 256, 0, stream>>>(
            delta, u, dbc, lAlog, Pbuf, Qbuf);
        scan_apply_kernel<<<dim3(DI / 16, NC, BB), 256, 0, stream>>>(
            delta, u, dbc, xr, lAlog, lDp, Pbuf, Qbuf, y16);

        // tmp = y @ out_w + out_b + x   (M x DM, K=DI)  [MFMA, 2-phase]
        gemm_mfma_bt<<<16 * 6, 256, 0, stream>>>(
            y16, lw_outT, lob, x, tmp, MM, DM, DI, 16, 6);

        // x = rmsnorm(tmp)  (f32 + bf16)
        rmsnorm_kernel<<<MM, 256, 0, stream>>>(tmp, lnw, x, x16);
    }

    // xf = rmsnorm(x)  (bf16 only)
    rmsnorm_kernel<<<MM, 256, 0, stream>>>(x, normf_w, nullptr, x16);

    // logits = xf @ emb^T   (M=2048, N=50264 pad 50304, K=768)  [MFMA, 2-phase]
    gemm_mfma_bt<<<16 * (VPAD / 128), 256, 0, stream>>>(
        x16, emb16, nullptr, nullptr, out, MM, VV, DM, 16, VPAD / 128);
}

// Round 7
// 1127.946 us; speedup vs baseline: 1.0769x; 1.0138x over previous
//
#include <hip/hip_runtime.h>
#include <math.h>
#include <stdint.h>

#define BB 2
#define LL 1024
#define DM 768
#define NL 2
#define VV 50264
#define VPAD 50304   // 393 * 128
#define DS 16
#define DI 1536
#define DR 48
#define DC 4
#define MM (BB*LL)

#define CH 64
#define NC (LL/CH)

#define TS 64
#define KT 16

typedef __attribute__((ext_vector_type(8))) short short8;
typedef __attribute__((ext_vector_type(4))) float f32x4;

#define AS3(p) ((__attribute__((address_space(3))) unsigned int*)(unsigned int)(uintptr_t)(p))
#define AS1(p) ((const __attribute__((address_space(1))) unsigned int*)(uintptr_t)(p))

__device__ __forceinline__ unsigned short f2bf(float v) {
    union { float f; unsigned u; } x; x.f = v;
    unsigned r = x.u + 0x7fffu + ((x.u >> 16) & 1u);
    return (unsigned short)(r >> 16);
}

// ---------------- embedding gather (f32 + bf16) ----------------
__global__ __launch_bounds__(256) void embed_kernel(
    const int* __restrict__ ids, const float* __restrict__ emb,
    float* __restrict__ x, unsigned short* __restrict__ x16)
{
    int m = blockIdx.x;
    int v = ids[m];
    const float* src = emb + (size_t)v * DM;
    float* dst = x + (size_t)m * DM;
    unsigned short* dst16 = x16 + (size_t)m * DM;
    for (int i = threadIdx.x; i < DM; i += 256) {
        float f = src[i];
        dst[i] = f;
        dst16[i] = f2bf(f);
    }
}

// ---------------- emb f32 [VV][DM] -> bf16 [VPAD][DM] (pad rows = 0), vectorized ----------------
__global__ __launch_bounds__(256) void emb_convert_kernel(
    const float* __restrict__ emb, unsigned short* __restrict__ out)
{
    size_t i8 = (size_t)blockIdx.x * 256 + threadIdx.x;
    size_t row = i8 / 96;
    size_t col8 = (i8 - row * 96) * 8;
    if (row >= VPAD) return;
    ushort4 o0, o1;
    if (row < VV) {
        const float* p = emb + row * DM + col8;
        float4 v0 = *(const float4*)p;
        float4 v1 = *(const float4*)(p + 4);
        o0.x = f2bf(v0.x); o0.y = f2bf(v0.y); o0.z = f2bf(v0.z); o0.w = f2bf(v0.w);
        o1.x = f2bf(v1.x); o1.y = f2bf(v1.y); o1.z = f2bf(v1.z); o1.w = f2bf(v1.w);
    } else {
        o0 = make_ushort4(0, 0, 0, 0);
        o1 = o0;
    }
    unsigned short* op = out + row * DM + col8;
    *(ushort4*)op = o0;
    *(ushort4*)(op + 4) = o1;
}

// ---------------- transpose+convert: in [L][R][C] f32 -> out [L][C][R] bf16 ----------------
__global__ __launch_bounds__(256) void transpose_bf16_kernel(
    const float* __restrict__ in, unsigned short* __restrict__ out, int R, int C)
{
    __shared__ float t[32][33];
    int l = blockIdx.z;
    int r0 = blockIdx.y * 32, c0 = blockIdx.x * 32;
    int tx = threadIdx.x & 31, ty = threadIdx.x >> 5;   // 32 x 8
    const float* ip = in + (size_t)l * R * C;
    unsigned short* op = out + (size_t)l * C * R;
    #pragma unroll
    for (int j = 0; j < 32; j += 8)
        t[ty + j][tx] = ip[(size_t)(r0 + ty + j) * C + c0 + tx];
    __syncthreads();
    #pragma unroll
    for (int j = 0; j < 32; j += 8)
        op[(size_t)(c0 + ty + j) * R + r0 + tx] = f2bf(t[tx][ty + j]);
}

// ---------------- MFMA bf16 GEMM: C = A[M,K] * B[Npad,K]^T (+bias) (+resid) ----------------
// 128x128 tile, BK=32, 4 waves. Depth-2 pipeline: 3 LDS buffers; iter t stages
// K-tile t+2 while computing tile t; barrier is raw s_barrier preceded by
// counted s_waitcnt vmcnt(4) (tile t+2's 4 loads stay in flight across the
// barrier; in-order vmcnt accounting guarantees tile t+1 has landed).
// XCD-bijective swizzle, m-tile fastest within an XCD chunk.
__global__ __launch_bounds__(256) void gemm_mfma_bt(
    const unsigned short* __restrict__ A, const unsigned short* __restrict__ B,
    const float* __restrict__ bias, const float* __restrict__ resid,
    float* __restrict__ C, int M, int N, int K, int MT, int NTILES)
{
    // XCD-bijective remap (m204)
    int T = MT * NTILES;
    int q = T >> 3, r = T & 7;
    int orig = blockIdx.x;
    int xcd = orig & 7, u = orig >> 3;
    int wg = (xcd < r ? xcd * (q + 1) : r * (q + 1) + (xcd - r) * q) + u;
    int mt = wg % MT, nt = wg / MT;

    __shared__ unsigned short As[3][128 * 32];
    __shared__ unsigned short Bs[3][128 * 32];
    int tid = threadIdx.x;
    int w = tid >> 6, lane = tid & 63;
    int m0 = mt * 128, n0 = nt * 128;

    int rA = lane >> 2;            // row within 16-row group
    int kb = (lane & 3) * 8;       // bf16 offset within row
    const unsigned short* gA0 = A + (size_t)(m0 + w * 16 + rA) * K + kb;
    const unsigned short* gA1 = gA0 + (size_t)64 * K;
    const unsigned short* gB0 = B + (size_t)(n0 + w * 16 + rA) * K + kb;
    const unsigned short* gB1 = gB0 + (size_t)64 * K;

    int lr = lane & 15, lk = lane >> 4;
    int wr = (w >> 1) * 64, wc = (w & 1) * 64;

    f32x4 acc[4][4] = {};

#define STAGE(k0, buf) do { \
    __builtin_amdgcn_global_load_lds(AS1(gA0 + (k0)), AS3(&As[buf][(w * 16) * 32]), 16, 0, 0); \
    __builtin_amdgcn_global_load_lds(AS1(gA1 + (k0)), AS3(&As[buf][(64 + w * 16) * 32]), 16, 0, 0); \
    __builtin_amdgcn_global_load_lds(AS1(gB0 + (k0)), AS3(&Bs[buf][(w * 16) * 32]), 16, 0, 0); \
    __builtin_amdgcn_global_load_lds(AS1(gB1 + (k0)), AS3(&Bs[buf][(64 + w * 16) * 32]), 16, 0, 0); \
} while (0)

#define COMPUTE(buf) do { \
    short8 a[4], b[4]; \
    _Pragma("unroll") \
    for (int f = 0; f < 4; ++f) \
        a[f] = *(const short8*)&As[buf][(wr + f * 16 + lr) * 32 + lk * 8]; \
    _Pragma("unroll") \
    for (int f = 0; f < 4; ++f) \
        b[f] = *(const short8*)&Bs[buf][(wc + f * 16 + lr) * 32 + lk * 8]; \
    _Pragma("unroll") \
    for (int i = 0; i < 4; ++i) \
        _Pragma("unroll") \
        for (int j = 0; j < 4; ++j) \
            acc[i][j] = __builtin_amdgcn_mfma_f32_16x16x32_bf16(a[i], b[j], acc[i][j], 0, 0, 0); \
} while (0)

    int nsteps = K / 32;               // always >= 2 here (K = 768 or 1536)
    STAGE(0, 0);
    STAGE(32, 1);
    // tile 0 must be resident; tile 1's 4 loads may remain in flight
    asm volatile("s_waitcnt vmcnt(4)" ::: "memory");
    __builtin_amdgcn_s_barrier();
    __builtin_amdgcn_sched_barrier(0);

    for (int t = 0; t < nsteps; ++t) {
        int cur = t % 3;
        if (t + 2 < nsteps)
            STAGE((t + 2) * 32, (t + 2) % 3);   // depth-2 prefetch
        COMPUTE(cur);
        if (t + 1 < nsteps) {
            if (t + 2 < nsteps)
                asm volatile("s_waitcnt vmcnt(4)" ::: "memory");  // t+1 landed; t+2 in flight
            else
                asm volatile("s_waitcnt vmcnt(0)" ::: "memory");  // drain tail
            __builtin_amdgcn_s_barrier();
            __builtin_amdgcn_sched_barrier(0);
        }
    }

#undef STAGE
#undef COMPUTE

    #pragma unroll
    for (int i = 0; i < 4; ++i) {
        int row = m0 + wr + i * 16 + lk * 4;
        #pragma unroll
        for (int j = 0; j < 4; ++j) {
            int col = n0 + wc + j * 16 + lr;
            if (col < N) {
                float bv = bias ? bias[col] : 0.f;
                #pragma unroll
                for (int r2 = 0; r2 < 4; ++r2) {
                    float v = acc[i][j][r2] + bv;
                    if (resid) v += resid[(size_t)(row + r2) * N + col];
                    C[(size_t)(row + r2) * N + col] = v;
                }
            }
        }
    }
}

// ---------------- f32 tiled GEMM (small shapes: xproj, dt) ----------------
template<int ACT>
__global__ __launch_bounds__(256) void gemm_tiled(
    const float* __restrict__ A, const float* __restrict__ Bm,
    const float* __restrict__ bias, float* __restrict__ C,
    int M, int N, int K, int lda)
{
    __shared__ float As[KT][TS + 4];
    __shared__ float Bs[KT][TS + 4];
    int tid = threadIdx.x;
    int tx = tid & 15, ty = tid >> 4;
    int m0 = blockIdx.y * TS;
    int n0 = blockIdx.x * TS;
    float acc[4][4] = {};

    for (int k0 = 0; k0 < K; k0 += KT) {
        {
            int i = tid >> 2;
            int k4 = (tid & 3) * 4;
            int m = m0 + i;
            float4 v = make_float4(0.f, 0.f, 0.f, 0.f);
            if (m < M) v = *(const float4*)(A + (size_t)m * lda + k0 + k4);
            As[k4 + 0][i] = v.x; As[k4 + 1][i] = v.y;
            As[k4 + 2][i] = v.z; As[k4 + 3][i] = v.w;
        }
        {
            int k = tid >> 4;
            int j4 = (tid & 15) * 4;
            int n = n0 + j4;
            float4 v = make_float4(0.f, 0.f, 0.f, 0.f);
            const float* p = Bm + (size_t)(k0 + k) * N + n;
            if (n + 3 < N) {
                v = *(const float4*)p;
            } else {
                float t0 = (n + 0 < N) ? p[0] : 0.f;
                float t1 = (n + 1 < N) ? p[1] : 0.f;
                float t2 = (n + 2 < N) ? p[2] : 0.f;
                float t3 = (n + 3 < N) ? p[3] : 0.f;
                v = make_float4(t0, t1, t2, t3);
            }
            Bs[k][j4 + 0] = v.x; Bs[k][j4 + 1] = v.y;
            Bs[k][j4 + 2] = v.z; Bs[k][j4 + 3] = v.w;
        }
        __syncthreads();
        #pragma unroll
        for (int k = 0; k < KT; ++k) {
            float a[4], b[4];
            #pragma unroll
            for (int q = 0; q < 4; ++q) a[q] = As[k][ty * 4 + q];
            #pragma unroll
            for (int q = 0; q < 4; ++q) b[q] = Bs[k][tx * 4 + q];
            #pragma unroll
            for (int i = 0; i < 4; ++i)
                #pragma unroll
                for (int j = 0; j < 4; ++j)
                    acc[i][j] = fmaf(a[i], b[j], acc[i][j]);
        }
        __syncthreads();
    }

    #pragma unroll
    for (int i = 0; i < 4; ++i) {
        int m = m0 + ty * 4 + i;
        if (m >= M) continue;
        #pragma unroll
        for (int j = 0; j < 4; ++j) {
            int n = n0 + tx * 4 + j;
            if (n >= N) continue;
            float v = acc[i][j];
            if (bias)  v += bias[n];
            if (ACT == 1) v = fmaxf(v, 0.f) + log1pf(expf(-fabsf(v)));
            C[(size_t)m * N + n] = v;
        }
    }
}

// ---------------- causal depthwise conv1d + SiLU ----------------
__global__ __launch_bounds__(256) void conv_silu_kernel(
    const float* __restrict__ xr, const float* __restrict__ cw,
    const float* __restrict__ cb, float* __restrict__ u)
{
    int d = blockIdx.x * 256 + threadIdx.x;
    int l = blockIdx.y;
    int b = blockIdx.z;
    float acc = cb[d];
    #pragma unroll
    for (int j = 0; j < DC; ++j) {
        int lp = l - (DC - 1) + j;
        if (lp >= 0)
            acc = fmaf(xr[((size_t)(b * LL + lp)) * (2 * DI) + d], cw[d * DC + j], acc);
    }
    float s = acc / (1.f + expf(-acc));
    u[((size_t)(b * LL + l)) * DI + d] = s;
}

// ---------------- chunked selective scan ----------------
__global__ __launch_bounds__(256) void scan_reduce_kernel(
    const float* __restrict__ delta, const float* __restrict__ u,
    const float* __restrict__ dbc, const float* __restrict__ A_log,
    float* __restrict__ P, float* __restrict__ Q)
{
    int tid = threadIdx.x;
    int n = tid & 15;
    int d = blockIdx.x * 16 + (tid >> 4);
    int c = blockIdx.y;
    int b = blockIdx.z;

    float Av = -expf(A_log[(size_t)d * DS + n]);
    float inv_Aeps = 1.f / (Av + 1e-7f);

    const float* dp = delta + ((size_t)b * LL + c * CH) * DI + d;
    const float* up = u     + ((size_t)b * LL + c * CH) * DI + d;
    const float* bp = dbc   + ((size_t)b * LL + c * CH) * 80 + DR + n;

    float p = 1.f, s = 0.f;
    for (int l = 0; l < CH; ++l) {
        float dlt = dp[(size_t)l * DI];
        float uv  = up[(size_t)l * DI];
        float Bv  = bp[(size_t)l * 80];
        float dA  = expf(dlt * Av);
        float dBu = (dA - 1.f) * inv_Aeps * Bv * uv;
        p *= dA;
        s = fmaf(dA, s, dBu);
    }
    size_t idx = (((size_t)b * NC + c) * DI + d) * DS + n;
    P[idx] = p;
    Q[idx] = s;
}

__global__ __launch_bounds__(256) void scan_apply_kernel(
    const float* __restrict__ delta, const float* __restrict__ u,
    const float* __restrict__ dbc, const float* __restrict__ xr,
    const float* __restrict__ A_log, const float* __restrict__ Dp,
    const float* __restrict__ P, const float* __restrict__ Q,
    unsigned short* __restrict__ y16)
{
    int tid = threadIdx.x;
    int n = tid & 15;
    int d = blockIdx.x * 16 + (tid >> 4);
    int c = blockIdx.y;
    int b = blockIdx.z;

    float Av = -expf(A_log[(size_t)d * DS + n]);
    float Dv = Dp[d];
    float inv_Aeps = 1.f / (Av + 1e-7f);

    float s = 0.f;
    for (int cc = 0; cc < c; ++cc) {
        size_t idx = (((size_t)b * NC + cc) * DI + d) * DS + n;
        s = fmaf(P[idx], s, Q[idx]);
    }

    const float* dp = delta + ((size_t)b * LL + c * CH) * DI + d;
    const float* up = u     + ((size_t)b * LL + c * CH) * DI + d;
    const float* xp = xr    + ((size_t)b * LL + c * CH) * (2 * DI) + DI + d;
    const float* bp = dbc   + ((size_t)b * LL + c * CH) * 80 + DR + n;
    const float* cp = dbc   + ((size_t)b * LL + c * CH) * 80 + DR + DS + n;
    unsigned short* yp = y16 + ((size_t)b * LL + c * CH) * DI + d;

    for (int l = 0; l < CH; ++l) {
        float dlt = dp[(size_t)l * DI];
        float uv  = up[(size_t)l * DI];
        float Bv  = bp[(size_t)l * 80];
        float Cv  = cp[(size_t)l * 80];
        float dA  = expf(dlt * Av);
        float dBu = (dA - 1.f) * inv_Aeps * Bv * uv;
        s = fmaf(dA, s, dBu);
        float pv = s * Cv;
        pv += __shfl_xor(pv, 1);
        pv += __shfl_xor(pv, 2);
        pv += __shfl_xor(pv, 4);
        pv += __shfl_xor(pv, 8);
        if (n == 0) {
            float rv = xp[(size_t)l * (2 * DI)];
            float res = rv / (1.f + expf(-rv));
            yp[(size_t)l * DI] = f2bf((pv + uv * Dv) * res);
        }
    }
}

// ---------------- RMSNorm (optional f32 out, optional bf16 out) ----------------
__global__ __launch_bounds__(256) void rmsnorm_kernel(
    const float* __restrict__ in, const float* __restrict__ w,
    float* __restrict__ outf, unsigned short* __restrict__ outb)
{
    int m = blockIdx.x;
    const float* row = in + (size_t)m * DM;
    float ss = 0.f;
    for (int i = threadIdx.x; i < DM; i += 256) { float v = row[i]; ss = fmaf(v, v, ss); }
    #pragma unroll
    for (int off = 32; off > 0; off >>= 1) ss += __shfl_down(ss, off);
    __shared__ float sred[4];
    __shared__ float sscale;
    int wid = threadIdx.x >> 6;
    if ((threadIdx.x & 63) == 0) sred[wid] = ss;
    __syncthreads();
    if (threadIdx.x == 0) {
        float tot = sred[0] + sred[1] + sred[2] + sred[3];
        sscale = 1.f / sqrtf(tot / (float)DM + 1e-5f);
    }
    __syncthreads();
    float sc = sscale;
    for (int i = threadIdx.x; i < DM; i += 256) {
        float v = row[i] * sc * w[i];
        if (outf) outf[(size_t)m * DM + i] = v;
        if (outb) outb[(size_t)m * DM + i] = f2bf(v);
    }
}

// ---------------- launch ----------------
extern "C" void kernel_launch(void* const* d_in, const int* in_sizes, int n_in,
                              void* d_out, int out_size, void* d_ws, size_t ws_size,
                              hipStream_t stream)
{
    const int*   ids      = (const int*)  d_in[0];
    const float* emb      = (const float*)d_in[1];
    const float* in_w     = (const float*)d_in[2];
    const float* in_b     = (const float*)d_in[3];
    const float* conv_w   = (const float*)d_in[4];
    const float* conv_b   = (const float*)d_in[5];
    const float* xproj_w  = (const float*)d_in[6];
    const float* dt_w     = (const float*)d_in[7];
    const float* dt_b     = (const float*)d_in[8];
    const float* A_log    = (const float*)d_in[9];
    const float* Dp       = (const float*)d_in[10];
    const float* out_w    = (const float*)d_in[11];
    const float* out_b    = (const float*)d_in[12];
    const float* norm_w   = (const float*)d_in[13];
    const float* normf_w  = (const float*)d_in[14];
    float* out = (float*)d_out;

    char* wsp = (char*)d_ws;
    auto alloc = [&](size_t bytes) {
        char* p = wsp;
        wsp += (bytes + 255) & ~(size_t)255;
        return p;
    };
    float* x     = (float*)alloc((size_t)MM * DM * 4);
    float* xr    = (float*)alloc((size_t)MM * 2 * DI * 4);
    float* u     = (float*)alloc((size_t)MM * DI * 4);
    float* dbc   = (float*)alloc((size_t)MM * 80 * 4);
    float* delta = (float*)alloc((size_t)MM * DI * 4);
    float* tmp   = (float*)alloc((size_t)MM * DM * 4);
    float* Pbuf  = (float*)alloc((size_t)BB * NC * DI * DS * 4);
    float* Qbuf  = (float*)alloc((size_t)BB * NC * DI * DS * 4);
    unsigned short* x16     = (unsigned short*)alloc((size_t)MM * DM * 2);
    unsigned short* y16     = (unsigned short*)alloc((size_t)MM * DI * 2);
    unsigned short* emb16   = (unsigned short*)alloc((size_t)VPAD * DM * 2);
    unsigned short* in_wT   = (unsigned short*)alloc((size_t)NL * 2 * DI * DM * 2);
    unsigned short* out_wT  = (unsigned short*)alloc((size_t)NL * DM * DI * 2);

    emb_convert_kernel<<<(VPAD * (DM / 8) + 255) / 256, 256, 0, stream>>>(emb, emb16);
    transpose_bf16_kernel<<<dim3(2 * DI / 32, DM / 32, NL), 256, 0, stream>>>(
        in_w, in_wT, DM, 2 * DI);
    transpose_bf16_kernel<<<dim3(DM / 32, DI / 32, NL), 256, 0, stream>>>(
        out_w, out_wT, DI, DM);

    embed_kernel<<<MM, 256, 0, stream>>>(ids, emb, x, x16);

    for (int layer = 0; layer < NL; ++layer) {
        const float* lb_in  = in_b    + (size_t)layer * 2 * DI;
        const float* lcw    = conv_w  + (size_t)layer * DI * DC;
        const float* lcb    = conv_b  + (size_t)layer * DI;
        const float* lxw    = xproj_w + (size_t)layer * DI * (DR + 2 * DS);
        const float* ldtw   = dt_w    + (size_t)layer * DR * DI;
        const float* ldtb   = dt_b    + (size_t)layer * DI;
        const float* lAlog  = A_log   + (size_t)layer * DI * DS;
        const float* lDp    = Dp      + (size_t)layer * DI;
        const float* lob    = out_b   + (size_t)layer * DM;
        const float* lnw    = norm_w  + (size_t)layer * DM;
        const unsigned short* lw_inT = in_wT  + (size_t)layer * 2 * DI * DM;
        const unsigned short* lw_outT= out_wT + (size_t)layer * DM * DI;

        // xr = x @ in_w + in_b   (M=2048, N=3072, K=768)  [MFMA, depth-2]
        gemm_mfma_bt<<<16 * 24, 256, 0, stream>>>(
            x16, lw_inT, lb_in, nullptr, xr, MM, 2 * DI, DM, 16, 24);

        conv_silu_kernel<<<dim3(DI / 256, LL, BB), 256, 0, stream>>>(xr, lcw, lcb, u);

        gemm_tiled<0><<<dim3(2, MM / TS), 256, 0, stream>>>(
            u, lxw, nullptr, dbc, MM, DR + 2 * DS, DI, DI);

        gemm_tiled<1><<<dim3(DI / TS, MM / TS), 256, 0, stream>>>(
            dbc, ldtw, ldtb, delta, MM, DI, DR, DR + 2 * DS);

        scan_reduce_kernel<<<dim3(DI / 16, NC, BB), 256, 0, stream>>>(
            delta, u, dbc, lAlog, Pbuf, Qbuf);
        scan_apply_kernel<<<dim3(DI / 16, NC, BB), 256, 0, stream>>>(
            delta, u, dbc, xr, lAlog, lDp, Pbuf, Qbuf, y16);

        // tmp = y @ out_w + out_b + x   (M x DM, K=DI)  [MFMA, depth-2]
        gemm_mfma_bt<<<16 * 6, 256, 0, stream>>>(
            y16, lw_outT, lob, x, tmp, MM, DM, DI, 16, 6);

        // x = rmsnorm(tmp)  (f32 + bf16)
        rmsnorm_kernel<<<MM, 256, 0, stream>>>(tmp, lnw, x, x16);
    }

    // xf = rmsnorm(x)  (bf16 only)
    rmsnorm_kernel<<<MM, 256, 0, stream>>>(x, normf_w, nullptr, x16);

    // logits = xf @ emb^T   (M=2048, N=50264 pad 50304, K=768)  [MFMA, depth-2]
    gemm_mfma_bt<<<16 * (VPAD / 128), 256, 0, stream>>>(
        x16, emb16, nullptr, nullptr, out, MM, VV, DM, 16, VPAD / 128);
}

// Round 8
// 861.839 us; speedup vs baseline: 1.4094x; 1.3088x over previous
//
#include <hip/hip_runtime.h>
#include <math.h>
#include <stdint.h>

#define BB 2
#define LL 1024
#define DM 768
#define NL 2
#define VV 50264
#define VPAD 50304   // 393 * 128
#define DS 16
#define DI 1536
#define DR 48
#define DC 4
#define MM (BB*LL)

#define CH 32
#define NC (LL/CH)   // 32

#define KS 8         // xproj K-split

#define TS 64
#define KT 16

typedef __attribute__((ext_vector_type(8))) short short8;
typedef __attribute__((ext_vector_type(4))) float f32x4;

#define AS3(p) ((__attribute__((address_space(3))) unsigned int*)(unsigned int)(uintptr_t)(p))
#define AS1(p) ((const __attribute__((address_space(1))) unsigned int*)(uintptr_t)(p))

__device__ __forceinline__ unsigned short f2bf(float v) {
    union { float f; unsigned u; } x; x.f = v;
    unsigned r = x.u + 0x7fffu + ((x.u >> 16) & 1u);
    return (unsigned short)(r >> 16);
}

// ---------------- embedding gather (f32 + bf16) ----------------
__global__ __launch_bounds__(256) void embed_kernel(
    const int* __restrict__ ids, const float* __restrict__ emb,
    float* __restrict__ x, unsigned short* __restrict__ x16)
{
    int m = blockIdx.x;
    int v = ids[m];
    const float* src = emb + (size_t)v * DM;
    float* dst = x + (size_t)m * DM;
    unsigned short* dst16 = x16 + (size_t)m * DM;
    for (int i = threadIdx.x; i < DM; i += 256) {
        float f = src[i];
        dst[i] = f;
        dst16[i] = f2bf(f);
    }
}

// ---------------- emb f32 [VV][DM] -> bf16 [VPAD][DM] (pad rows = 0), vectorized ----------------
__global__ __launch_bounds__(256) void emb_convert_kernel(
    const float* __restrict__ emb, unsigned short* __restrict__ out)
{
    size_t i8 = (size_t)blockIdx.x * 256 + threadIdx.x;
    size_t row = i8 / 96;
    size_t col8 = (i8 - row * 96) * 8;
    if (row >= VPAD) return;
    ushort4 o0, o1;
    if (row < VV) {
        const float* p = emb + row * DM + col8;
        float4 v0 = *(const float4*)p;
        float4 v1 = *(const float4*)(p + 4);
        o0.x = f2bf(v0.x); o0.y = f2bf(v0.y); o0.z = f2bf(v0.z); o0.w = f2bf(v0.w);
        o1.x = f2bf(v1.x); o1.y = f2bf(v1.y); o1.z = f2bf(v1.z); o1.w = f2bf(v1.w);
    } else {
        o0 = make_ushort4(0, 0, 0, 0);
        o1 = o0;
    }
    unsigned short* op = out + row * DM + col8;
    *(ushort4*)op = o0;
    *(ushort4*)(op + 4) = o1;
}

// ---------------- transpose+convert: in [L][R][C] f32 -> out [L][C][R] bf16 ----------------
__global__ __launch_bounds__(256) void transpose_bf16_kernel(
    const float* __restrict__ in, unsigned short* __restrict__ out, int R, int C)
{
    __shared__ float t[32][33];
    int l = blockIdx.z;
    int r0 = blockIdx.y * 32, c0 = blockIdx.x * 32;
    int tx = threadIdx.x & 31, ty = threadIdx.x >> 5;   // 32 x 8
    const float* ip = in + (size_t)l * R * C;
    unsigned short* op = out + (size_t)l * C * R;
    #pragma unroll
    for (int j = 0; j < 32; j += 8)
        t[ty + j][tx] = ip[(size_t)(r0 + ty + j) * C + c0 + tx];
    __syncthreads();
    #pragma unroll
    for (int j = 0; j < 32; j += 8)
        op[(size_t)(c0 + ty + j) * R + r0 + tx] = f2bf(t[tx][ty + j]);
}

// ---------------- MFMA bf16 GEMM: C = A[M,K] * B[Npad,K]^T (+bias) (+resid) ----------------
// 128x128 tile, BK=32, 4 waves, depth-2 pipeline (3 LDS buffers, counted vmcnt).
__global__ __launch_bounds__(256) void gemm_mfma_bt(
    const unsigned short* __restrict__ A, const unsigned short* __restrict__ B,
    const float* __restrict__ bias, const float* __restrict__ resid,
    float* __restrict__ C, int M, int N, int K, int MT, int NTILES)
{
    // XCD-bijective remap (m204)
    int T = MT * NTILES;
    int q = T >> 3, r = T & 7;
    int orig = blockIdx.x;
    int xcd = orig & 7, u = orig >> 3;
    int wg = (xcd < r ? xcd * (q + 1) : r * (q + 1) + (xcd - r) * q) + u;
    int mt = wg % MT, nt = wg / MT;

    __shared__ unsigned short As[3][128 * 32];
    __shared__ unsigned short Bs[3][128 * 32];
    int tid = threadIdx.x;
    int w = tid >> 6, lane = tid & 63;
    int m0 = mt * 128, n0 = nt * 128;

    int rA = lane >> 2;
    int kb = (lane & 3) * 8;
    const unsigned short* gA0 = A + (size_t)(m0 + w * 16 + rA) * K + kb;
    const unsigned short* gA1 = gA0 + (size_t)64 * K;
    const unsigned short* gB0 = B + (size_t)(n0 + w * 16 + rA) * K + kb;
    const unsigned short* gB1 = gB0 + (size_t)64 * K;

    int lr = lane & 15, lk = lane >> 4;
    int wr = (w >> 1) * 64, wc = (w & 1) * 64;

    f32x4 acc[4][4] = {};

#define STAGE(k0, buf) do { \
    __builtin_amdgcn_global_load_lds(AS1(gA0 + (k0)), AS3(&As[buf][(w * 16) * 32]), 16, 0, 0); \
    __builtin_amdgcn_global_load_lds(AS1(gA1 + (k0)), AS3(&As[buf][(64 + w * 16) * 32]), 16, 0, 0); \
    __builtin_amdgcn_global_load_lds(AS1(gB0 + (k0)), AS3(&Bs[buf][(w * 16) * 32]), 16, 0, 0); \
    __builtin_amdgcn_global_load_lds(AS1(gB1 + (k0)), AS3(&Bs[buf][(64 + w * 16) * 32]), 16, 0, 0); \
} while (0)

#define COMPUTE(buf) do { \
    short8 a[4], b[4]; \
    _Pragma("unroll") \
    for (int f = 0; f < 4; ++f) \
        a[f] = *(const short8*)&As[buf][(wr + f * 16 + lr) * 32 + lk * 8]; \
    _Pragma("unroll") \
    for (int f = 0; f < 4; ++f) \
        b[f] = *(const short8*)&Bs[buf][(wc + f * 16 + lr) * 32 + lk * 8]; \
    _Pragma("unroll") \
    for (int i = 0; i < 4; ++i) \
        _Pragma("unroll") \
        for (int j = 0; j < 4; ++j) \
            acc[i][j] = __builtin_amdgcn_mfma_f32_16x16x32_bf16(a[i], b[j], acc[i][j], 0, 0, 0); \
} while (0)

    int nsteps = K / 32;
    STAGE(0, 0);
    STAGE(32, 1);
    asm volatile("s_waitcnt vmcnt(4)" ::: "memory");
    __builtin_amdgcn_s_barrier();
    __builtin_amdgcn_sched_barrier(0);

    for (int t = 0; t < nsteps; ++t) {
        int cur = t % 3;
        if (t + 2 < nsteps)
            STAGE((t + 2) * 32, (t + 2) % 3);
        COMPUTE(cur);
        if (t + 1 < nsteps) {
            if (t + 2 < nsteps)
                asm volatile("s_waitcnt vmcnt(4)" ::: "memory");
            else
                asm volatile("s_waitcnt vmcnt(0)" ::: "memory");
            __builtin_amdgcn_s_barrier();
            __builtin_amdgcn_sched_barrier(0);
        }
    }

#undef STAGE
#undef COMPUTE

    #pragma unroll
    for (int i = 0; i < 4; ++i) {
        int row = m0 + wr + i * 16 + lk * 4;
        #pragma unroll
        for (int j = 0; j < 4; ++j) {
            int col = n0 + wc + j * 16 + lr;
            if (col < N) {
                float bv = bias ? bias[col] : 0.f;
                #pragma unroll
                for (int r2 = 0; r2 < 4; ++r2) {
                    float v = acc[i][j][r2] + bv;
                    if (resid) v += resid[(size_t)(row + r2) * N + col];
                    C[(size_t)(row + r2) * N + col] = v;
                }
            }
        }
    }
}

// ---------------- f32 tiled GEMM (dt: N=1536, K=48) ----------------
template<int ACT>
__global__ __launch_bounds__(256) void gemm_tiled(
    const float* __restrict__ A, const float* __restrict__ Bm,
    const float* __restrict__ bias, float* __restrict__ C,
    int M, int N, int K, int lda)
{
    __shared__ float As[KT][TS + 4];
    __shared__ float Bs[KT][TS + 4];
    int tid = threadIdx.x;
    int tx = tid & 15, ty = tid >> 4;
    int m0 = blockIdx.y * TS;
    int n0 = blockIdx.x * TS;
    float acc[4][4] = {};

    for (int k0 = 0; k0 < K; k0 += KT) {
        {
            int i = tid >> 2;
            int k4 = (tid & 3) * 4;
            int m = m0 + i;
            float4 v = make_float4(0.f, 0.f, 0.f, 0.f);
            if (m < M) v = *(const float4*)(A + (size_t)m * lda + k0 + k4);
            As[k4 + 0][i] = v.x; As[k4 + 1][i] = v.y;
            As[k4 + 2][i] = v.z; As[k4 + 3][i] = v.w;
        }
        {
            int k = tid >> 4;
            int j4 = (tid & 15) * 4;
            int n = n0 + j4;
            float4 v = make_float4(0.f, 0.f, 0.f, 0.f);
            const float* p = Bm + (size_t)(k0 + k) * N + n;
            if (n + 3 < N) {
                v = *(const float4*)p;
            } else {
                float t0 = (n + 0 < N) ? p[0] : 0.f;
                float t1 = (n + 1 < N) ? p[1] : 0.f;
                float t2 = (n + 2 < N) ? p[2] : 0.f;
                float t3 = (n + 3 < N) ? p[3] : 0.f;
                v = make_float4(t0, t1, t2, t3);
            }
            Bs[k][j4 + 0] = v.x; Bs[k][j4 + 1] = v.y;
            Bs[k][j4 + 2] = v.z; Bs[k][j4 + 3] = v.w;
        }
        __syncthreads();
        #pragma unroll
        for (int k = 0; k < KT; ++k) {
            float a[4], b[4];
            #pragma unroll
            for (int q2 = 0; q2 < 4; ++q2) a[q2] = As[k][ty * 4 + q2];
            #pragma unroll
            for (int q2 = 0; q2 < 4; ++q2) b[q2] = Bs[k][tx * 4 + q2];
            #pragma unroll
            for (int i = 0; i < 4; ++i)
                #pragma unroll
                for (int j = 0; j < 4; ++j)
                    acc[i][j] = fmaf(a[i], b[j], acc[i][j]);
        }
        __syncthreads();
    }

    #pragma unroll
    for (int i = 0; i < 4; ++i) {
        int m = m0 + ty * 4 + i;
        if (m >= M) continue;
        #pragma unroll
        for (int j = 0; j < 4; ++j) {
            int n = n0 + tx * 4 + j;
            if (n >= N) continue;
            float v = acc[i][j];
            if (bias)  v += bias[n];
            if (ACT == 1) v = fmaxf(v, 0.f) + log1pf(expf(-fabsf(v)));
            C[(size_t)m * N + n] = v;
        }
    }
}

// ---------------- xproj partial GEMM: part[z] = u @ xproj_w over K-range z ----------------
// grid (2, MM/64, KS); each z covers K in [z*DI/KS, (z+1)*DI/KS)
__global__ __launch_bounds__(256) void xproj_part_kernel(
    const float* __restrict__ A, const float* __restrict__ Bm, float* __restrict__ part)
{
    __shared__ float As[KT][TS + 4];
    __shared__ float Bs[KT][TS + 4];
    int tid = threadIdx.x;
    int tx = tid & 15, ty = tid >> 4;
    int m0 = blockIdx.y * TS;
    int n0 = blockIdx.x * TS;
    int kbeg = blockIdx.z * (DI / KS);
    const int N = 80;
    float acc[4][4] = {};

    for (int k0 = kbeg; k0 < kbeg + DI / KS; k0 += KT) {
        {
            int i = tid >> 2;
            int k4 = (tid & 3) * 4;
            float4 v = *(const float4*)(A + (size_t)(m0 + i) * DI + k0 + k4);
            As[k4 + 0][i] = v.x; As[k4 + 1][i] = v.y;
            As[k4 + 2][i] = v.z; As[k4 + 3][i] = v.w;
        }
        {
            int k = tid >> 4;
            int j4 = (tid & 15) * 4;
            int n = n0 + j4;
            const float* p = Bm + (size_t)(k0 + k) * N + n;
            float4 v;
            if (n + 3 < N) {
                v = *(const float4*)p;
            } else {
                v.x = (n + 0 < N) ? p[0] : 0.f;
                v.y = (n + 1 < N) ? p[1] : 0.f;
                v.z = (n + 2 < N) ? p[2] : 0.f;
                v.w = (n + 3 < N) ? p[3] : 0.f;
            }
            Bs[k][j4 + 0] = v.x; Bs[k][j4 + 1] = v.y;
            Bs[k][j4 + 2] = v.z; Bs[k][j4 + 3] = v.w;
        }
        __syncthreads();
        #pragma unroll
        for (int k = 0; k < KT; ++k) {
            float a[4], b[4];
            #pragma unroll
            for (int q2 = 0; q2 < 4; ++q2) a[q2] = As[k][ty * 4 + q2];
            #pragma unroll
            for (int q2 = 0; q2 < 4; ++q2) b[q2] = Bs[k][tx * 4 + q2];
            #pragma unroll
            for (int i = 0; i < 4; ++i)
                #pragma unroll
                for (int j = 0; j < 4; ++j)
                    acc[i][j] = fmaf(a[i], b[j], acc[i][j]);
        }
        __syncthreads();
    }

    float* op = part + (size_t)blockIdx.z * MM * 80;
    #pragma unroll
    for (int i = 0; i < 4; ++i) {
        int m = m0 + ty * 4 + i;
        #pragma unroll
        for (int j = 0; j < 4; ++j) {
            int n = n0 + tx * 4 + j;
            if (n < 80) op[(size_t)m * 80 + n] = acc[i][j];
        }
    }
}

__global__ __launch_bounds__(256) void xproj_reduce_kernel(
    const float* __restrict__ part, float* __restrict__ dbc)
{
    int i = blockIdx.x * 256 + threadIdx.x;
    if (i >= MM * 80) return;
    float s = 0.f;
    #pragma unroll
    for (int z = 0; z < KS; ++z) s += part[(size_t)z * MM * 80 + i];
    dbc[i] = s;
}

// ---------------- causal depthwise conv1d + SiLU ----------------
__global__ __launch_bounds__(256) void conv_silu_kernel(
    const float* __restrict__ xr, const float* __restrict__ cw,
    const float* __restrict__ cb, float* __restrict__ u)
{
    int d = blockIdx.x * 256 + threadIdx.x;
    int l = blockIdx.y;
    int b = blockIdx.z;
    float acc = cb[d];
    #pragma unroll
    for (int j = 0; j < DC; ++j) {
        int lp = l - (DC - 1) + j;
        if (lp >= 0)
            acc = fmaf(xr[((size_t)(b * LL + lp)) * (2 * DI) + d], cw[d * DC + j], acc);
    }
    float s = acc / (1.f + expf(-acc));
    u[((size_t)(b * LL + l)) * DI + d] = s;
}

// ---------------- chunked selective scan, lane-per-d layout ----------------
// Each thread owns one d and all 16 n-states in registers.
// grid (DI/256, NC, BB), 256 threads.
__global__ __launch_bounds__(256) void scan_reduce_kernel(
    const float* __restrict__ delta, const float* __restrict__ u,
    const float* __restrict__ dbc, const float* __restrict__ A_log,
    float* __restrict__ P, float* __restrict__ Q)
{
    int d = blockIdx.x * 256 + threadIdx.x;
    int c = blockIdx.y;
    int b = blockIdx.z;

    float Av[DS], invA[DS];
    {
        const float4* ap = (const float4*)(A_log + (size_t)d * DS);
        #pragma unroll
        for (int n4 = 0; n4 < 4; ++n4) {
            float4 a = ap[n4];
            Av[n4 * 4 + 0] = -expf(a.x); Av[n4 * 4 + 1] = -expf(a.y);
            Av[n4 * 4 + 2] = -expf(a.z); Av[n4 * 4 + 3] = -expf(a.w);
        }
        #pragma unroll
        for (int n = 0; n < DS; ++n) invA[n] = 1.f / (Av[n] + 1e-7f);
    }

    float p[DS], s[DS];
    #pragma unroll
    for (int n = 0; n < DS; ++n) { p[n] = 1.f; s[n] = 0.f; }

    const float* dp = delta + ((size_t)b * LL + c * CH) * DI + d;
    const float* up = u     + ((size_t)b * LL + c * CH) * DI + d;
    const float* bb = dbc   + ((size_t)b * LL + c * CH) * 80 + DR;

    for (int l = 0; l < CH; ++l) {
        float dlt = dp[(size_t)l * DI];
        float uv  = up[(size_t)l * DI];
        float Bv[DS];
        {
            const float4* bp4 = (const float4*)(bb + (size_t)l * 80);
            #pragma unroll
            for (int n4 = 0; n4 < 4; ++n4) {
                float4 v = bp4[n4];
                Bv[n4 * 4 + 0] = v.x; Bv[n4 * 4 + 1] = v.y;
                Bv[n4 * 4 + 2] = v.z; Bv[n4 * 4 + 3] = v.w;
            }
        }
        #pragma unroll
        for (int n = 0; n < DS; ++n) {
            float dA = expf(dlt * Av[n]);
            float dBu = (dA - 1.f) * invA[n] * Bv[n] * uv;
            p[n] *= dA;
            s[n] = fmaf(dA, s[n], dBu);
        }
    }

    float* Pp = P + (((size_t)b * NC + c) * DI + d) * DS;
    float* Qp = Q + (((size_t)b * NC + c) * DI + d) * DS;
    #pragma unroll
    for (int n4 = 0; n4 < 4; ++n4) {
        ((float4*)Pp)[n4] = make_float4(p[n4 * 4 + 0], p[n4 * 4 + 1], p[n4 * 4 + 2], p[n4 * 4 + 3]);
        ((float4*)Qp)[n4] = make_float4(s[n4 * 4 + 0], s[n4 * 4 + 1], s[n4 * 4 + 2], s[n4 * 4 + 3]);
    }
}

__global__ __launch_bounds__(256) void scan_apply_kernel(
    const float* __restrict__ delta, const float* __restrict__ u,
    const float* __restrict__ dbc, const float* __restrict__ xr,
    const float* __restrict__ A_log, const float* __restrict__ Dp,
    const float* __restrict__ P, const float* __restrict__ Q,
    unsigned short* __restrict__ y16)
{
    int d = blockIdx.x * 256 + threadIdx.x;
    int c = blockIdx.y;
    int b = blockIdx.z;

    float Av[DS], invA[DS];
    {
        const float4* ap = (const float4*)(A_log + (size_t)d * DS);
        #pragma unroll
        for (int n4 = 0; n4 < 4; ++n4) {
            float4 a = ap[n4];
            Av[n4 * 4 + 0] = -expf(a.x); Av[n4 * 4 + 1] = -expf(a.y);
            Av[n4 * 4 + 2] = -expf(a.z); Av[n4 * 4 + 3] = -expf(a.w);
        }
        #pragma unroll
        for (int n = 0; n < DS; ++n) invA[n] = 1.f / (Av[n] + 1e-7f);
    }
    float Dv = Dp[d];

    // prefix over preceding chunks (P,Q are 64B-contiguous per (c,d))
    float s[DS];
    #pragma unroll
    for (int n = 0; n < DS; ++n) s[n] = 0.f;
    for (int cc = 0; cc < c; ++cc) {
        const float* Pp = P + (((size_t)b * NC + cc) * DI + d) * DS;
        const float* Qp = Q + (((size_t)b * NC + cc) * DI + d) * DS;
        float pv[DS], qv[DS];
        #pragma unroll
        for (int n4 = 0; n4 < 4; ++n4) {
            float4 pw = ((const float4*)Pp)[n4];
            float4 qw = ((const float4*)Qp)[n4];
            pv[n4 * 4 + 0] = pw.x; pv[n4 * 4 + 1] = pw.y; pv[n4 * 4 + 2] = pw.z; pv[n4 * 4 + 3] = pw.w;
            qv[n4 * 4 + 0] = qw.x; qv[n4 * 4 + 1] = qw.y; qv[n4 * 4 + 2] = qw.z; qv[n4 * 4 + 3] = qw.w;
        }
        #pragma unroll
        for (int n = 0; n < DS; ++n) s[n] = fmaf(pv[n], s[n], qv[n]);
    }

    const float* dp = delta + ((size_t)b * LL + c * CH) * DI + d;
    const float* up = u     + ((size_t)b * LL + c * CH) * DI + d;
    const float* xp = xr    + ((size_t)b * LL + c * CH) * (2 * DI) + DI + d;
    const float* bb = dbc   + ((size_t)b * LL + c * CH) * 80 + DR;
    unsigned short* yp = y16 + ((size_t)b * LL + c * CH) * DI + d;

    for (int l = 0; l < CH; ++l) {
        float dlt = dp[(size_t)l * DI];
        float uv  = up[(size_t)l * DI];
        float rv  = xp[(size_t)l * (2 * DI)];
        float Bv[DS], Cv[DS];
        {
            const float4* bp4 = (const float4*)(bb + (size_t)l * 80);
            #pragma unroll
            for (int n4 = 0; n4 < 4; ++n4) {
                float4 v = bp4[n4];
                Bv[n4 * 4 + 0] = v.x; Bv[n4 * 4 + 1] = v.y;
                Bv[n4 * 4 + 2] = v.z; Bv[n4 * 4 + 3] = v.w;
            }
            #pragma unroll
            for (int n4 = 0; n4 < 4; ++n4) {
                float4 v = bp4[4 + n4];
                Cv[n4 * 4 + 0] = v.x; Cv[n4 * 4 + 1] = v.y;
                Cv[n4 * 4 + 2] = v.z; Cv[n4 * 4 + 3] = v.w;
            }
        }
        float pv = 0.f;
        #pragma unroll
        for (int n = 0; n < DS; ++n) {
            float dA = expf(dlt * Av[n]);
            float dBu = (dA - 1.f) * invA[n] * Bv[n] * uv;
            s[n] = fmaf(dA, s[n], dBu);
            pv = fmaf(s[n], Cv[n], pv);
        }
        float res = rv / (1.f + expf(-rv));
        yp[(size_t)l * DI] = f2bf((pv + uv * Dv) * res);
    }
}

// ---------------- RMSNorm (optional f32 out, optional bf16 out) ----------------
__global__ __launch_bounds__(256) void rmsnorm_kernel(
    const float* __restrict__ in, const float* __restrict__ w,
    float* __restrict__ outf, unsigned short* __restrict__ outb)
{
    int m = blockIdx.x;
    const float* row = in + (size_t)m * DM;
    float ss = 0.f;
    for (int i = threadIdx.x; i < DM; i += 256) { float v = row[i]; ss = fmaf(v, v, ss); }
    #pragma unroll
    for (int off = 32; off > 0; off >>= 1) ss += __shfl_down(ss, off);
    __shared__ float sred[4];
    __shared__ float sscale;
    int wid = threadIdx.x >> 6;
    if ((threadIdx.x & 63) == 0) sred[wid] = ss;
    __syncthreads();
    if (threadIdx.x == 0) {
        float tot = sred[0] + sred[1] + sred[2] + sred[3];
        sscale = 1.f / sqrtf(tot / (float)DM + 1e-5f);
    }
    __syncthreads();
    float sc = sscale;
    for (int i = threadIdx.x; i < DM; i += 256) {
        float v = row[i] * sc * w[i];
        if (outf) outf[(size_t)m * DM + i] = v;
        if (outb) outb[(size_t)m * DM + i] = f2bf(v);
    }
}

// ---------------- launch ----------------
extern "C" void kernel_launch(void* const* d_in, const int* in_sizes, int n_in,
                              void* d_out, int out_size, void* d_ws, size_t ws_size,
                              hipStream_t stream)
{
    const int*   ids      = (const int*)  d_in[0];
    const float* emb      = (const float*)d_in[1];
    const float* in_w     = (const float*)d_in[2];
    const float* in_b     = (const float*)d_in[3];
    const float* conv_w   = (const float*)d_in[4];
    const float* conv_b   = (const float*)d_in[5];
    const float* xproj_w  = (const float*)d_in[6];
    const float* dt_w     = (const float*)d_in[7];
    const float* dt_b     = (const float*)d_in[8];
    const float* A_log    = (const float*)d_in[9];
    const float* Dp       = (const float*)d_in[10];
    const float* out_w    = (const float*)d_in[11];
    const float* out_b    = (const float*)d_in[12];
    const float* norm_w   = (const float*)d_in[13];
    const float* normf_w  = (const float*)d_in[14];
    float* out = (float*)d_out;

    char* wsp = (char*)d_ws;
    auto alloc = [&](size_t bytes) {
        char* p = wsp;
        wsp += (bytes + 255) & ~(size_t)255;
        return p;
    };
    float* x     = (float*)alloc((size_t)MM * DM * 4);
    float* xr    = (float*)alloc((size_t)MM * 2 * DI * 4);
    float* u     = (float*)alloc((size_t)MM * DI * 4);
    float* dbc   = (float*)alloc((size_t)MM * 80 * 4);
    float* part  = (float*)alloc((size_t)KS * MM * 80 * 4);
    float* delta = (float*)alloc((size_t)MM * DI * 4);
    float* tmp   = (float*)alloc((size_t)MM * DM * 4);
    float* Pbuf  = (float*)alloc((size_t)BB * NC * DI * DS * 4);
    float* Qbuf  = (float*)alloc((size_t)BB * NC * DI * DS * 4);
    unsigned short* x16     = (unsigned short*)alloc((size_t)MM * DM * 2);
    unsigned short* y16     = (unsigned short*)alloc((size_t)MM * DI * 2);
    unsigned short* emb16   = (unsigned short*)alloc((size_t)VPAD * DM * 2);
    unsigned short* in_wT   = (unsigned short*)alloc((size_t)NL * 2 * DI * DM * 2);
    unsigned short* out_wT  = (unsigned short*)alloc((size_t)NL * DM * DI * 2);

    emb_convert_kernel<<<(VPAD * (DM / 8) + 255) / 256, 256, 0, stream>>>(emb, emb16);
    transpose_bf16_kernel<<<dim3(2 * DI / 32, DM / 32, NL), 256, 0, stream>>>(
        in_w, in_wT, DM, 2 * DI);
    transpose_bf16_kernel<<<dim3(DM / 32, DI / 32, NL), 256, 0, stream>>>(
        out_w, out_wT, DI, DM);

    embed_kernel<<<MM, 256, 0, stream>>>(ids, emb, x, x16);

    for (int layer = 0; layer < NL; ++layer) {
        const float* lb_in  = in_b    + (size_t)layer * 2 * DI;
        const float* lcw    = conv_w  + (size_t)layer * DI * DC;
        const float* lcb    = conv_b  + (size_t)layer * DI;
        const float* lxw    = xproj_w + (size_t)layer * DI * (DR + 2 * DS);
        const float* ldtw   = dt_w    + (size_t)layer * DR * DI;
        const float* ldtb   = dt_b    + (size_t)layer * DI;
        const float* lAlog  = A_log   + (size_t)layer * DI * DS;
        const float* lDp    = Dp      + (size_t)layer * DI;
        const float* lob    = out_b   + (size_t)layer * DM;
        const float* lnw    = norm_w  + (size_t)layer * DM;
        const unsigned short* lw_inT = in_wT  + (size_t)layer * 2 * DI * DM;
        const unsigned short* lw_outT= out_wT + (size_t)layer * DM * DI;

        // xr = x @ in_w + in_b   [MFMA]
        gemm_mfma_bt<<<16 * 24, 256, 0, stream>>>(
            x16, lw_inT, lb_in, nullptr, xr, MM, 2 * DI, DM, 16, 24);

        conv_silu_kernel<<<dim3(DI / 256, LL, BB), 256, 0, stream>>>(xr, lcw, lcb, u);

        // dbc = u @ xproj_w  via K-split partials + reduce
        xproj_part_kernel<<<dim3(2, MM / TS, KS), 256, 0, stream>>>(u, lxw, part);
        xproj_reduce_kernel<<<(MM * 80 + 255) / 256, 256, 0, stream>>>(part, dbc);

        // delta = softplus(dbc[:, :48] @ dt_w + dt_b)
        gemm_tiled<1><<<dim3(DI / TS, MM / TS), 256, 0, stream>>>(
            dbc, ldtw, ldtb, delta, MM, DI, DR, DR + 2 * DS);

        // chunked scan, lane-per-d
        scan_reduce_kernel<<<dim3(DI / 256, NC, BB), 256, 0, stream>>>(
            delta, u, dbc, lAlog, Pbuf, Qbuf);
        scan_apply_kernel<<<dim3(DI / 256, NC, BB), 256, 0, stream>>>(
            delta, u, dbc, xr, lAlog, lDp, Pbuf, Qbuf, y16);

        // tmp = y @ out_w + out_b + x   [MFMA]
        gemm_mfma_bt<<<16 * 6, 256, 0, stream>>>(
            y16, lw_outT, lob, x, tmp, MM, DM, DI, 16, 6);

        rmsnorm_kernel<<<MM, 256, 0, stream>>>(tmp, lnw, x, x16);
    }

    rmsnorm_kernel<<<MM, 256, 0, stream>>>(x, normf_w, nullptr, x16);

    // logits = xf @ emb^T   [MFMA]
    gemm_mfma_bt<<<16 * (VPAD / 128), 256, 0, stream>>>(
        x16, emb16, nullptr, nullptr, out, MM, VV, DM, 16, VPAD / 128);
}

// Round 9
// 810.899 us; speedup vs baseline: 1.4979x; 1.0628x over previous
//
#include <hip/hip_runtime.h>
#include <math.h>
#include <stdint.h>

#define BB 2
#define LL 1024
#define DM 768
#define NL 2
#define VV 50264
#define VP2 50432    // 197 * 256 (pad for 256-wide tiles)
#define DS 16
#define DI 1536
#define DR 48
#define DC 4
#define MM (BB*LL)

#define CH 32
#define NC (LL/CH)   // 32

#define KS 8         // xproj K-split

#define TS 64
#define KT 16

typedef __attribute__((ext_vector_type(8))) short short8;
typedef __attribute__((ext_vector_type(4))) float f32x4;

#define AS3(p) ((__attribute__((address_space(3))) unsigned int*)(unsigned int)(uintptr_t)(p))
#define AS1(p) ((const __attribute__((address_space(1))) unsigned int*)(uintptr_t)(p))

__device__ __forceinline__ unsigned short f2bf(float v) {
    union { float f; unsigned u; } x; x.f = v;
    unsigned r = x.u + 0x7fffu + ((x.u >> 16) & 1u);
    return (unsigned short)(r >> 16);
}

// ---------------- embedding gather (f32 + bf16) ----------------
__global__ __launch_bounds__(256) void embed_kernel(
    const int* __restrict__ ids, const float* __restrict__ emb,
    float* __restrict__ x, unsigned short* __restrict__ x16)
{
    int m = blockIdx.x;
    int v = ids[m];
    const float* src = emb + (size_t)v * DM;
    float* dst = x + (size_t)m * DM;
    unsigned short* dst16 = x16 + (size_t)m * DM;
    for (int i = threadIdx.x; i < DM; i += 256) {
        float f = src[i];
        dst[i] = f;
        dst16[i] = f2bf(f);
    }
}

// ---------------- emb f32 [VV][DM] -> bf16 [VP2][DM] (pad rows = 0), vectorized ----------------
__global__ __launch_bounds__(256) void emb_convert_kernel(
    const float* __restrict__ emb, unsigned short* __restrict__ out)
{
    size_t i8 = (size_t)blockIdx.x * 256 + threadIdx.x;
    size_t row = i8 / 96;
    size_t col8 = (i8 - row * 96) * 8;
    if (row >= VP2) return;
    ushort4 o0, o1;
    if (row < VV) {
        const float* p = emb + row * DM + col8;
        float4 v0 = *(const float4*)p;
        float4 v1 = *(const float4*)(p + 4);
        o0.x = f2bf(v0.x); o0.y = f2bf(v0.y); o0.z = f2bf(v0.z); o0.w = f2bf(v0.w);
        o1.x = f2bf(v1.x); o1.y = f2bf(v1.y); o1.z = f2bf(v1.z); o1.w = f2bf(v1.w);
    } else {
        o0 = make_ushort4(0, 0, 0, 0);
        o1 = o0;
    }
    unsigned short* op = out + row * DM + col8;
    *(ushort4*)op = o0;
    *(ushort4*)(op + 4) = o1;
}

// ---------------- transpose+convert: in [L][R][C] f32 -> out [L][C][R] bf16 ----------------
__global__ __launch_bounds__(256) void transpose_bf16_kernel(
    const float* __restrict__ in, unsigned short* __restrict__ out, int R, int C)
{
    __shared__ float t[32][33];
    int l = blockIdx.z;
    int r0 = blockIdx.y * 32, c0 = blockIdx.x * 32;
    int tx = threadIdx.x & 31, ty = threadIdx.x >> 5;   // 32 x 8
    const float* ip = in + (size_t)l * R * C;
    unsigned short* op = out + (size_t)l * C * R;
    #pragma unroll
    for (int j = 0; j < 32; j += 8)
        t[ty + j][tx] = ip[(size_t)(r0 + ty + j) * C + c0 + tx];
    __syncthreads();
    #pragma unroll
    for (int j = 0; j < 32; j += 8)
        op[(size_t)(c0 + ty + j) * R + r0 + tx] = f2bf(t[tx][ty + j]);
}

// ---------------- 128x128 MFMA GEMM (in-proj / out-proj) ----------------
__global__ __launch_bounds__(256) void gemm_mfma_bt(
    const unsigned short* __restrict__ A, const unsigned short* __restrict__ B,
    const float* __restrict__ bias, const float* __restrict__ resid,
    float* __restrict__ C, int M, int N, int K, int MT, int NTILES)
{
    int T = MT * NTILES;
    int q = T >> 3, r = T & 7;
    int orig = blockIdx.x;
    int xcd = orig & 7, u = orig >> 3;
    int wg = (xcd < r ? xcd * (q + 1) : r * (q + 1) + (xcd - r) * q) + u;
    int mt = wg % MT, nt = wg / MT;

    __shared__ unsigned short As[3][128 * 32];
    __shared__ unsigned short Bs[3][128 * 32];
    int tid = threadIdx.x;
    int w = tid >> 6, lane = tid & 63;
    int m0 = mt * 128, n0 = nt * 128;

    int rA = lane >> 2;
    int kb = (lane & 3) * 8;
    const unsigned short* gA0 = A + (size_t)(m0 + w * 16 + rA) * K + kb;
    const unsigned short* gA1 = gA0 + (size_t)64 * K;
    const unsigned short* gB0 = B + (size_t)(n0 + w * 16 + rA) * K + kb;
    const unsigned short* gB1 = gB0 + (size_t)64 * K;

    int lr = lane & 15, lk = lane >> 4;
    int wr = (w >> 1) * 64, wc = (w & 1) * 64;

    f32x4 acc[4][4] = {};

#define STAGE(k0, buf) do { \
    __builtin_amdgcn_global_load_lds(AS1(gA0 + (k0)), AS3(&As[buf][(w * 16) * 32]), 16, 0, 0); \
    __builtin_amdgcn_global_load_lds(AS1(gA1 + (k0)), AS3(&As[buf][(64 + w * 16) * 32]), 16, 0, 0); \
    __builtin_amdgcn_global_load_lds(AS1(gB0 + (k0)), AS3(&Bs[buf][(w * 16) * 32]), 16, 0, 0); \
    __builtin_amdgcn_global_load_lds(AS1(gB1 + (k0)), AS3(&Bs[buf][(64 + w * 16) * 32]), 16, 0, 0); \
} while (0)

#define COMPUTE(buf) do { \
    short8 a[4], b[4]; \
    _Pragma("unroll") \
    for (int f = 0; f < 4; ++f) \
        a[f] = *(const short8*)&As[buf][(wr + f * 16 + lr) * 32 + lk * 8]; \
    _Pragma("unroll") \
    for (int f = 0; f < 4; ++f) \
        b[f] = *(const short8*)&Bs[buf][(wc + f * 16 + lr) * 32 + lk * 8]; \
    _Pragma("unroll") \
    for (int i = 0; i < 4; ++i) \
        _Pragma("unroll") \
        for (int j = 0; j < 4; ++j) \
            acc[i][j] = __builtin_amdgcn_mfma_f32_16x16x32_bf16(a[i], b[j], acc[i][j], 0, 0, 0); \
} while (0)

    int nsteps = K / 32;
    STAGE(0, 0);
    STAGE(32, 1);
    asm volatile("s_waitcnt vmcnt(4)" ::: "memory");
    __builtin_amdgcn_s_barrier();
    __builtin_amdgcn_sched_barrier(0);

    for (int t = 0; t < nsteps; ++t) {
        int cur = t % 3;
        if (t + 2 < nsteps)
            STAGE((t + 2) * 32, (t + 2) % 3);
        COMPUTE(cur);
        if (t + 1 < nsteps) {
            if (t + 2 < nsteps)
                asm volatile("s_waitcnt vmcnt(4)" ::: "memory");
            else
                asm volatile("s_waitcnt vmcnt(0)" ::: "memory");
            __builtin_amdgcn_s_barrier();
            __builtin_amdgcn_sched_barrier(0);
        }
    }

#undef STAGE
#undef COMPUTE

    #pragma unroll
    for (int i = 0; i < 4; ++i) {
        int row = m0 + wr + i * 16 + lk * 4;
        #pragma unroll
        for (int j = 0; j < 4; ++j) {
            int col = n0 + wc + j * 16 + lr;
            if (col < N) {
                float bv = bias ? bias[col] : 0.f;
                #pragma unroll
                for (int r2 = 0; r2 < 4; ++r2) {
                    float v = acc[i][j][r2] + bv;
                    if (resid) v += resid[(size_t)(row + r2) * N + col];
                    C[(size_t)(row + r2) * N + col] = v;
                }
            }
        }
    }
}

// ---------------- 256x256 phase-split MFMA GEMM (logits) ----------------
// BK=32, 3 K-tile LDS slots, 8 waves (2m x 4n), per-wave 128x64 output.
// Per K-tile: 2 phases {ds-reads | stage 2 loads of tile t+2 | barrier |
// lgkmcnt(0) | setprio(1) 16 MFMA setprio(0) | barrier}; boundary vmcnt(4).
// T2 chunk-swizzle sigma(r)=(r&3)^((r>>2)&3): linear LDS dest (global_load_lds),
// inverse-swizzled per-lane GLOBAL source, swizzled ds_read chunk (rule #21).
__global__ __launch_bounds__(512) void gemm_mfma_256(
    const unsigned short* __restrict__ A, const unsigned short* __restrict__ B,
    float* __restrict__ C, int M, int N, int K, int MT, int NTILES)
{
    int T = MT * NTILES;
    int q = T >> 3, r = T & 7;
    int orig = blockIdx.x;
    int xcd = orig & 7, u = orig >> 3;
    int wg = (xcd < r ? xcd * (q + 1) : r * (q + 1) + (xcd - r) * q) + u;
    int mt = wg % MT, nt = wg / MT;

    __shared__ unsigned short As[3][256 * 32];
    __shared__ unsigned short Bs[3][256 * 32];
    int tid = threadIdx.x;
    int w = tid >> 6, lane = tid & 63;
    int wm = w >> 2, wn = w & 3;
    int m0 = mt * 256, n0 = nt * 256;

    // staging: thread covers rows (tid>>2) and 128+(tid>>2); swizzled source chunk
    int srow = tid >> 2;                                   // 0..127
    int schunk = (tid & 3) ^ ((srow & 3) ^ ((srow >> 2) & 3));
    const unsigned short* gA0 = A + (size_t)(m0 + srow) * K + schunk * 8;
    const unsigned short* gA1 = gA0 + (size_t)128 * K;
    const unsigned short* gB0 = B + (size_t)(n0 + srow) * K + schunk * 8;
    const unsigned short* gB1 = gB0 + (size_t)128 * K;

    // ds-read chunk offset (swizzled): sigma depends only on lr
    int lr = lane & 15, lk = lane >> 4;
    int rc = (lk ^ ((lr & 3) ^ ((lr >> 2) & 3))) * 8;      // ushort offset in row

    f32x4 acc[8][4] = {};

#define STAGE_A(k0, buf) do { \
    __builtin_amdgcn_global_load_lds(AS1(gA0 + (k0)), AS3(&As[buf][(w * 16) * 32]), 16, 0, 0); \
    __builtin_amdgcn_global_load_lds(AS1(gA1 + (k0)), AS3(&As[buf][(128 + w * 16) * 32]), 16, 0, 0); \
} while (0)
#define STAGE_B(k0, buf) do { \
    __builtin_amdgcn_global_load_lds(AS1(gB0 + (k0)), AS3(&Bs[buf][(w * 16) * 32]), 16, 0, 0); \
    __builtin_amdgcn_global_load_lds(AS1(gB1 + (k0)), AS3(&Bs[buf][(128 + w * 16) * 32]), 16, 0, 0); \
} while (0)

    int nsteps = K / 32;   // >= 2

    // prologue: tiles 0 and 1
    STAGE_A(0, 0); STAGE_B(0, 0);
    STAGE_A(32, 1); STAGE_B(32, 1);
    asm volatile("s_waitcnt vmcnt(4)" ::: "memory");   // tile0 landed; tile1 in flight
    __builtin_amdgcn_s_barrier();
    __builtin_amdgcn_sched_barrier(0);

    for (int t = 0; t < nsteps; ++t) {
        int s = t % 3;
        int sn = (t + 2) % 3;
        bool stage2 = (t + 2) < nsteps;
        short8 av[4], bv[4];

        // ---- phase 0: m-frags 0..3 ----
        #pragma unroll
        for (int f = 0; f < 4; ++f)
            av[f] = *(const short8*)&As[s][(wm * 128 + f * 16 + lr) * 32 + rc];
        #pragma unroll
        for (int f = 0; f < 4; ++f)
            bv[f] = *(const short8*)&Bs[s][(wn * 64 + f * 16 + lr) * 32 + rc];
        if (stage2) STAGE_A((t + 2) * 32, sn);
        __builtin_amdgcn_s_barrier();
        asm volatile("s_waitcnt lgkmcnt(0)" ::: "memory");
        __builtin_amdgcn_sched_barrier(0);
        __builtin_amdgcn_s_setprio(1);
        #pragma unroll
        for (int i = 0; i < 4; ++i)
            #pragma unroll
            for (int j = 0; j < 4; ++j)
                acc[i][j] = __builtin_amdgcn_mfma_f32_16x16x32_bf16(av[i], bv[j], acc[i][j], 0, 0, 0);
        __builtin_amdgcn_s_setprio(0);
        __builtin_amdgcn_s_barrier();

        // ---- phase 1: m-frags 4..7 (reuse bv) ----
        #pragma unroll
        for (int f = 0; f < 4; ++f)
            av[f] = *(const short8*)&As[s][(wm * 128 + (4 + f) * 16 + lr) * 32 + rc];
        if (stage2) STAGE_B((t + 2) * 32, sn);
        __builtin_amdgcn_s_barrier();
        asm volatile("s_waitcnt lgkmcnt(0)" ::: "memory");
        __builtin_amdgcn_sched_barrier(0);
        __builtin_amdgcn_s_setprio(1);
        #pragma unroll
        for (int i = 0; i < 4; ++i)
            #pragma unroll
            for (int j = 0; j < 4; ++j)
                acc[4 + i][j] = __builtin_amdgcn_mfma_f32_16x16x32_bf16(av[i], bv[j], acc[4 + i][j], 0, 0, 0);
        __builtin_amdgcn_s_setprio(0);

        // ---- tile boundary: tile t+1 must be resident ----
        if (t + 1 < nsteps) {
            if (stage2)
                asm volatile("s_waitcnt vmcnt(4)" ::: "memory");
            else
                asm volatile("s_waitcnt vmcnt(0)" ::: "memory");
            __builtin_amdgcn_s_barrier();
            __builtin_amdgcn_sched_barrier(0);
        }
    }

#undef STAGE_A
#undef STAGE_B

    #pragma unroll
    for (int i = 0; i < 8; ++i) {
        int row = m0 + wm * 128 + i * 16 + lk * 4;
        #pragma unroll
        for (int j = 0; j < 4; ++j) {
            int col = n0 + wn * 64 + j * 16 + lr;
            if (col < N) {
                #pragma unroll
                for (int r2 = 0; r2 < 4; ++r2)
                    C[(size_t)(row + r2) * N + col] = acc[i][j][r2];
            }
        }
    }
}

// ---------------- f32 tiled GEMM (dt: N=1536, K=48) ----------------
template<int ACT>
__global__ __launch_bounds__(256) void gemm_tiled(
    const float* __restrict__ A, const float* __restrict__ Bm,
    const float* __restrict__ bias, float* __restrict__ C,
    int M, int N, int K, int lda)
{
    __shared__ float As[KT][TS + 4];
    __shared__ float Bs[KT][TS + 4];
    int tid = threadIdx.x;
    int tx = tid & 15, ty = tid >> 4;
    int m0 = blockIdx.y * TS;
    int n0 = blockIdx.x * TS;
    float acc[4][4] = {};

    for (int k0 = 0; k0 < K; k0 += KT) {
        {
            int i = tid >> 2;
            int k4 = (tid & 3) * 4;
            int m = m0 + i;
            float4 v = make_float4(0.f, 0.f, 0.f, 0.f);
            if (m < M) v = *(const float4*)(A + (size_t)m * lda + k0 + k4);
            As[k4 + 0][i] = v.x; As[k4 + 1][i] = v.y;
            As[k4 + 2][i] = v.z; As[k4 + 3][i] = v.w;
        }
        {
            int k = tid >> 4;
            int j4 = (tid & 15) * 4;
            int n = n0 + j4;
            float4 v = make_float4(0.f, 0.f, 0.f, 0.f);
            const float* p = Bm + (size_t)(k0 + k) * N + n;
            if (n + 3 < N) {
                v = *(const float4*)p;
            } else {
                float t0 = (n + 0 < N) ? p[0] : 0.f;
                float t1 = (n + 1 < N) ? p[1] : 0.f;
                float t2 = (n + 2 < N) ? p[2] : 0.f;
                float t3 = (n + 3 < N) ? p[3] : 0.f;
                v = make_float4(t0, t1, t2, t3);
            }
            Bs[k][j4 + 0] = v.x; Bs[k][j4 + 1] = v.y;
            Bs[k][j4 + 2] = v.z; Bs[k][j4 + 3] = v.w;
        }
        __syncthreads();
        #pragma unroll
        for (int k = 0; k < KT; ++k) {
            float a[4], b[4];
            #pragma unroll
            for (int q2 = 0; q2 < 4; ++q2) a[q2] = As[k][ty * 4 + q2];
            #pragma unroll
            for (int q2 = 0; q2 < 4; ++q2) b[q2] = Bs[k][tx * 4 + q2];
            #pragma unroll
            for (int i = 0; i < 4; ++i)
                #pragma unroll
                for (int j = 0; j < 4; ++j)
                    acc[i][j] = fmaf(a[i], b[j], acc[i][j]);
        }
        __syncthreads();
    }

    #pragma unroll
    for (int i = 0; i < 4; ++i) {
        int m = m0 + ty * 4 + i;
        if (m >= M) continue;
        #pragma unroll
        for (int j = 0; j < 4; ++j) {
            int n = n0 + tx * 4 + j;
            if (n >= N) continue;
            float v = acc[i][j];
            if (bias)  v += bias[n];
            if (ACT == 1) v = fmaxf(v, 0.f) + log1pf(expf(-fabsf(v)));
            C[(size_t)m * N + n] = v;
        }
    }
}

// ---------------- xproj partial GEMM ----------------
__global__ __launch_bounds__(256) void xproj_part_kernel(
    const float* __restrict__ A, const float* __restrict__ Bm, float* __restrict__ part)
{
    __shared__ float As[KT][TS + 4];
    __shared__ float Bs[KT][TS + 4];
    int tid = threadIdx.x;
    int tx = tid & 15, ty = tid >> 4;
    int m0 = blockIdx.y * TS;
    int n0 = blockIdx.x * TS;
    int kbeg = blockIdx.z * (DI / KS);
    const int N = 80;
    float acc[4][4] = {};

    for (int k0 = kbeg; k0 < kbeg + DI / KS; k0 += KT) {
        {
            int i = tid >> 2;
            int k4 = (tid & 3) * 4;
            float4 v = *(const float4*)(A + (size_t)(m0 + i) * DI + k0 + k4);
            As[k4 + 0][i] = v.x; As[k4 + 1][i] = v.y;
            As[k4 + 2][i] = v.z; As[k4 + 3][i] = v.w;
        }
        {
            int k = tid >> 4;
            int j4 = (tid & 15) * 4;
            int n = n0 + j4;
            const float* p = Bm + (size_t)(k0 + k) * N + n;
            float4 v;
            if (n + 3 < N) {
                v = *(const float4*)p;
            } else {
                v.x = (n + 0 < N) ? p[0] : 0.f;
                v.y = (n + 1 < N) ? p[1] : 0.f;
                v.z = (n + 2 < N) ? p[2] : 0.f;
                v.w = (n + 3 < N) ? p[3] : 0.f;
            }
            Bs[k][j4 + 0] = v.x; Bs[k][j4 + 1] = v.y;
            Bs[k][j4 + 2] = v.z; Bs[k][j4 + 3] = v.w;
        }
        __syncthreads();
        #pragma unroll
        for (int k = 0; k < KT; ++k) {
            float a[4], b[4];
            #pragma unroll
            for (int q2 = 0; q2 < 4; ++q2) a[q2] = As[k][ty * 4 + q2];
            #pragma unroll
            for (int q2 = 0; q2 < 4; ++q2) b[q2] = Bs[k][tx * 4 + q2];
            #pragma unroll
            for (int i = 0; i < 4; ++i)
                #pragma unroll
                for (int j = 0; j < 4; ++j)
                    acc[i][j] = fmaf(a[i], b[j], acc[i][j]);
        }
        __syncthreads();
    }

    float* op = part + (size_t)blockIdx.z * MM * 80;
    #pragma unroll
    for (int i = 0; i < 4; ++i) {
        int m = m0 + ty * 4 + i;
        #pragma unroll
        for (int j = 0; j < 4; ++j) {
            int n = n0 + tx * 4 + j;
            if (n < 80) op[(size_t)m * 80 + n] = acc[i][j];
        }
    }
}

__global__ __launch_bounds__(256) void xproj_reduce_kernel(
    const float* __restrict__ part, float* __restrict__ dbc)
{
    int i = blockIdx.x * 256 + threadIdx.x;
    if (i >= MM * 80) return;
    float s = 0.f;
    #pragma unroll
    for (int z = 0; z < KS; ++z) s += part[(size_t)z * MM * 80 + i];
    dbc[i] = s;
}

// ---------------- causal depthwise conv1d + SiLU ----------------
__global__ __launch_bounds__(256) void conv_silu_kernel(
    const float* __restrict__ xr, const float* __restrict__ cw,
    const float* __restrict__ cb, float* __restrict__ u)
{
    int d = blockIdx.x * 256 + threadIdx.x;
    int l = blockIdx.y;
    int b = blockIdx.z;
    float acc = cb[d];
    #pragma unroll
    for (int j = 0; j < DC; ++j) {
        int lp = l - (DC - 1) + j;
        if (lp >= 0)
            acc = fmaf(xr[((size_t)(b * LL + lp)) * (2 * DI) + d], cw[d * DC + j], acc);
    }
    float s = acc / (1.f + expf(-acc));
    u[((size_t)(b * LL + l)) * DI + d] = s;
}

// ---------------- chunked selective scan, lane-per-d layout ----------------
__global__ __launch_bounds__(256) void scan_reduce_kernel(
    const float* __restrict__ delta, const float* __restrict__ u,
    const float* __restrict__ dbc, const float* __restrict__ A_log,
    float* __restrict__ P, float* __restrict__ Q)
{
    int d = blockIdx.x * 256 + threadIdx.x;
    int c = blockIdx.y;
    int b = blockIdx.z;

    float Av[DS], invA[DS];
    {
        const float4* ap = (const float4*)(A_log + (size_t)d * DS);
        #pragma unroll
        for (int n4 = 0; n4 < 4; ++n4) {
            float4 a = ap[n4];
            Av[n4 * 4 + 0] = -expf(a.x); Av[n4 * 4 + 1] = -expf(a.y);
            Av[n4 * 4 + 2] = -expf(a.z); Av[n4 * 4 + 3] = -expf(a.w);
        }
        #pragma unroll
        for (int n = 0; n < DS; ++n) invA[n] = 1.f / (Av[n] + 1e-7f);
    }

    float p[DS], s[DS];
    #pragma unroll
    for (int n = 0; n < DS; ++n) { p[n] = 1.f; s[n] = 0.f; }

    const float* dp = delta + ((size_t)b * LL + c * CH) * DI + d;
    const float* up = u     + ((size_t)b * LL + c * CH) * DI + d;
    const float* bb = dbc   + ((size_t)b * LL + c * CH) * 80 + DR;

    for (int l = 0; l < CH; ++l) {
        float dlt = dp[(size_t)l * DI];
        float uv  = up[(size_t)l * DI];
        float Bv[DS];
        {
            const float4* bp4 = (const float4*)(bb + (size_t)l * 80);
            #pragma unroll
            for (int n4 = 0; n4 < 4; ++n4) {
                float4 v = bp4[n4];
                Bv[n4 * 4 + 0] = v.x; Bv[n4 * 4 + 1] = v.y;
                Bv[n4 * 4 + 2] = v.z; Bv[n4 * 4 + 3] = v.w;
            }
        }
        #pragma unroll
        for (int n = 0; n < DS; ++n) {
            float dA = expf(dlt * Av[n]);
            float dBu = (dA - 1.f) * invA[n] * Bv[n] * uv;
            p[n] *= dA;
            s[n] = fmaf(dA, s[n], dBu);
        }
    }

    float* Pp = P + (((size_t)b * NC + c) * DI + d) * DS;
    float* Qp = Q + (((size_t)b * NC + c) * DI + d) * DS;
    #pragma unroll
    for (int n4 = 0; n4 < 4; ++n4) {
        ((float4*)Pp)[n4] = make_float4(p[n4 * 4 + 0], p[n4 * 4 + 1], p[n4 * 4 + 2], p[n4 * 4 + 3]);
        ((float4*)Qp)[n4] = make_float4(s[n4 * 4 + 0], s[n4 * 4 + 1], s[n4 * 4 + 2], s[n4 * 4 + 3]);
    }
}

__global__ __launch_bounds__(256) void scan_apply_kernel(
    const float* __restrict__ delta, const float* __restrict__ u,
    const float* __restrict__ dbc, const float* __restrict__ xr,
    const float* __restrict__ A_log, const float* __restrict__ Dp,
    const float* __restrict__ P, const float* __restrict__ Q,
    unsigned short* __restrict__ y16)
{
    int d = blockIdx.x * 256 + threadIdx.x;
    int c = blockIdx.y;
    int b = blockIdx.z;

    float Av[DS], invA[DS];
    {
        const float4* ap = (const float4*)(A_log + (size_t)d * DS);
        #pragma unroll
        for (int n4 = 0; n4 < 4; ++n4) {
            float4 a = ap[n4];
            Av[n4 * 4 + 0] = -expf(a.x); Av[n4 * 4 + 1] = -expf(a.y);
            Av[n4 * 4 + 2] = -expf(a.z); Av[n4 * 4 + 3] = -expf(a.w);
        }
        #pragma unroll
        for (int n = 0; n < DS; ++n) invA[n] = 1.f / (Av[n] + 1e-7f);
    }
    float Dv = Dp[d];

    float s[DS];
    #pragma unroll
    for (int n = 0; n < DS; ++n) s[n] = 0.f;
    for (int cc = 0; cc < c; ++cc) {
        const float* Pp = P + (((size_t)b * NC + cc) * DI + d) * DS;
        const float* Qp = Q + (((size_t)b * NC + cc) * DI + d) * DS;
        float pv[DS], qv[DS];
        #pragma unroll
        for (int n4 = 0; n4 < 4; ++n4) {
            float4 pw = ((const float4*)Pp)[n4];
            float4 qw = ((const float4*)Qp)[n4];
            pv[n4 * 4 + 0] = pw.x; pv[n4 * 4 + 1] = pw.y; pv[n4 * 4 + 2] = pw.z; pv[n4 * 4 + 3] = pw.w;
            qv[n4 * 4 + 0] = qw.x; qv[n4 * 4 + 1] = qw.y; qv[n4 * 4 + 2] = qw.z; qv[n4 * 4 + 3] = qw.w;
        }
        #pragma unroll
        for (int n = 0; n < DS; ++n) s[n] = fmaf(pv[n], s[n], qv[n]);
    }

    const float* dp = delta + ((size_t)b * LL + c * CH) * DI + d;
    const float* up = u     + ((size_t)b * LL + c * CH) * DI + d;
    const float* xp = xr    + ((size_t)b * LL + c * CH) * (2 * DI) + DI + d;
    const float* bb = dbc   + ((size_t)b * LL + c * CH) * 80 + DR;
    unsigned short* yp = y16 + ((size_t)b * LL + c * CH) * DI + d;

    for (int l = 0; l < CH; ++l) {
        float dlt = dp[(size_t)l * DI];
        float uv  = up[(size_t)l * DI];
        float rv  = xp[(size_t)l * (2 * DI)];
        float Bv[DS], Cv[DS];
        {
            const float4* bp4 = (const float4*)(bb + (size_t)l * 80);
            #pragma unroll
            for (int n4 = 0; n4 < 4; ++n4) {
                float4 v = bp4[n4];
                Bv[n4 * 4 + 0] = v.x; Bv[n4 * 4 + 1] = v.y;
                Bv[n4 * 4 + 2] = v.z; Bv[n4 * 4 + 3] = v.w;
            }
            #pragma unroll
            for (int n4 = 0; n4 < 4; ++n4) {
                float4 v = bp4[4 + n4];
                Cv[n4 * 4 + 0] = v.x; Cv[n4 * 4 + 1] = v.y;
                Cv[n4 * 4 + 2] = v.z; Cv[n4 * 4 + 3] = v.w;
            }
        }
        float pv = 0.f;
        #pragma unroll
        for (int n = 0; n < DS; ++n) {
            float dA = expf(dlt * Av[n]);
            float dBu = (dA - 1.f) * invA[n] * Bv[n] * uv;
            s[n] = fmaf(dA, s[n], dBu);
            pv = fmaf(s[n], Cv[n], pv);
        }
        float res = rv / (1.f + expf(-rv));
        yp[(size_t)l * DI] = f2bf((pv + uv * Dv) * res);
    }
}

// ---------------- RMSNorm ----------------
__global__ __launch_bounds__(256) void rmsnorm_kernel(
    const float* __restrict__ in, const float* __restrict__ w,
    float* __restrict__ outf, unsigned short* __restrict__ outb)
{
    int m = blockIdx.x;
    const float* row = in + (size_t)m * DM;
    float ss = 0.f;
    for (int i = threadIdx.x; i < DM; i += 256) { float v = row[i]; ss = fmaf(v, v, ss); }
    #pragma unroll
    for (int off = 32; off > 0; off >>= 1) ss += __shfl_down(ss, off);
    __shared__ float sred[4];
    __shared__ float sscale;
    int wid = threadIdx.x >> 6;
    if ((threadIdx.x & 63) == 0) sred[wid] = ss;
    __syncthreads();
    if (threadIdx.x == 0) {
        float tot = sred[0] + sred[1] + sred[2] + sred[3];
        sscale = 1.f / sqrtf(tot / (float)DM + 1e-5f);
    }
    __syncthreads();
    float sc = sscale;
    for (int i = threadIdx.x; i < DM; i += 256) {
        float v = row[i] * sc * w[i];
        if (outf) outf[(size_t)m * DM + i] = v;
        if (outb) outb[(size_t)m * DM + i] = f2bf(v);
    }
}

// ---------------- launch ----------------
extern "C" void kernel_launch(void* const* d_in, const int* in_sizes, int n_in,
                              void* d_out, int out_size, void* d_ws, size_t ws_size,
                              hipStream_t stream)
{
    const int*   ids      = (const int*)  d_in[0];
    const float* emb      = (const float*)d_in[1];
    const float* in_w     = (const float*)d_in[2];
    const float* in_b     = (const float*)d_in[3];
    const float* conv_w   = (const float*)d_in[4];
    const float* conv_b   = (const float*)d_in[5];
    const float* xproj_w  = (const float*)d_in[6];
    const float* dt_w     = (const float*)d_in[7];
    const float* dt_b     = (const float*)d_in[8];
    const float* A_log    = (const float*)d_in[9];
    const float* Dp       = (const float*)d_in[10];
    const float* out_w    = (const float*)d_in[11];
    const float* out_b    = (const float*)d_in[12];
    const float* norm_w   = (const float*)d_in[13];
    const float* normf_w  = (const float*)d_in[14];
    float* out = (float*)d_out;

    char* wsp = (char*)d_ws;
    auto alloc = [&](size_t bytes) {
        char* p = wsp;
        wsp += (bytes + 255) & ~(size_t)255;
        return p;
    };
    float* x     = (float*)alloc((size_t)MM * DM * 4);
    float* xr    = (float*)alloc((size_t)MM * 2 * DI * 4);
    float* u     = (float*)alloc((size_t)MM * DI * 4);
    float* dbc   = (float*)alloc((size_t)MM * 80 * 4);
    float* part  = (float*)alloc((size_t)KS * MM * 80 * 4);
    float* delta = (float*)alloc((size_t)MM * DI * 4);
    float* tmp   = (float*)alloc((size_t)MM * DM * 4);
    float* Pbuf  = (float*)alloc((size_t)BB * NC * DI * DS * 4);
    float* Qbuf  = (float*)alloc((size_t)BB * NC * DI * DS * 4);
    unsigned short* x16     = (unsigned short*)alloc((size_t)MM * DM * 2);
    unsigned short* y16     = (unsigned short*)alloc((size_t)MM * DI * 2);
    unsigned short* emb16   = (unsigned short*)alloc((size_t)VP2 * DM * 2);
    unsigned short* in_wT   = (unsigned short*)alloc((size_t)NL * 2 * DI * DM * 2);
    unsigned short* out_wT  = (unsigned short*)alloc((size_t)NL * DM * DI * 2);

    emb_convert_kernel<<<((size_t)VP2 * (DM / 8) + 255) / 256, 256, 0, stream>>>(emb, emb16);
    transpose_bf16_kernel<<<dim3(2 * DI / 32, DM / 32, NL), 256, 0, stream>>>(
        in_w, in_wT, DM, 2 * DI);
    transpose_bf16_kernel<<<dim3(DM / 32, DI / 32, NL), 256, 0, stream>>>(
        out_w, out_wT, DI, DM);

    embed_kernel<<<MM, 256, 0, stream>>>(ids, emb, x, x16);

    for (int layer = 0; layer < NL; ++layer) {
        const float* lb_in  = in_b    + (size_t)layer * 2 * DI;
        const float* lcw    = conv_w  + (size_t)layer * DI * DC;
        const float* lcb    = conv_b  + (size_t)layer * DI;
        const float* lxw    = xproj_w + (size_t)layer * DI * (DR + 2 * DS);
        const float* ldtw   = dt_w    + (size_t)layer * DR * DI;
        const float* ldtb   = dt_b    + (size_t)layer * DI;
        const float* lAlog  = A_log   + (size_t)layer * DI * DS;
        const float* lDp    = Dp      + (size_t)layer * DI;
        const float* lob    = out_b   + (size_t)layer * DM;
        const float* lnw    = norm_w  + (size_t)layer * DM;
        const unsigned short* lw_inT = in_wT  + (size_t)layer * 2 * DI * DM;
        const unsigned short* lw_outT= out_wT + (size_t)layer * DM * DI;

        gemm_mfma_bt<<<16 * 24, 256, 0, stream>>>(
            x16, lw_inT, lb_in, nullptr, xr, MM, 2 * DI, DM, 16, 24);

        conv_silu_kernel<<<dim3(DI / 256, LL, BB), 256, 0, stream>>>(xr, lcw, lcb, u);

        xproj_part_kernel<<<dim3(2, MM / TS, KS), 256, 0, stream>>>(u, lxw, part);
        xproj_reduce_kernel<<<(MM * 80 + 255) / 256, 256, 0, stream>>>(part, dbc);

        gemm_tiled<1><<<dim3(DI / TS, MM / TS), 256, 0, stream>>>(
            dbc, ldtw, ldtb, delta, MM, DI, DR, DR + 2 * DS);

        scan_reduce_kernel<<<dim3(DI / 256, NC, BB), 256, 0, stream>>>(
            delta, u, dbc, lAlog, Pbuf, Qbuf);
        scan_apply_kernel<<<dim3(DI / 256, NC, BB), 256, 0, stream>>>(
            delta, u, dbc, xr, lAlog, lDp, Pbuf, Qbuf, y16);

        gemm_mfma_bt<<<16 * 6, 256, 0, stream>>>(
            y16, lw_outT, lob, x, tmp, MM, DM, DI, 16, 6);

        rmsnorm_kernel<<<MM, 256, 0, stream>>>(tmp, lnw, x, x16);
    }

    rmsnorm_kernel<<<MM, 256, 0, stream>>>(x, normf_w, nullptr, x16);

    // logits = xf @ emb^T  (M=2048, N=50264 pad 50432, K=768)  [256x256 phase-split]
    gemm_mfma_256<<<8 * (VP2 / 256), 512, 0, stream>>>(
        x16, emb16, out, MM, VV, DM, 8, VP2 / 256);
}